// Round 1
// baseline (598.692 us; speedup 1.0000x reference)
//
#include <hip/hip_runtime.h>
#include <hip/hip_bf16.h>
#include <cstdint>

#define BATCH 32
#define NITEMS 16384
#define DEMB 128
#define IDIM 64

typedef short short8 __attribute__((ext_vector_type(8)));
typedef float f32x4 __attribute__((ext_vector_type(4)));
typedef unsigned short ushort4v __attribute__((ext_vector_type(4)));

// ---------- helpers ----------
__device__ inline unsigned short f2bf(float f) {
    union { float f; unsigned int u; } v; v.f = f;
    unsigned int u = v.u;
    unsigned int r = (u + 0x7FFFu + ((u >> 16) & 1u)) >> 16;   // RNE, data is finite
    return (unsigned short)r;
}
__device__ inline float bf2f(unsigned short h) {
    union { unsigned int u; float f; } v; v.u = ((unsigned int)h) << 16;
    return v.f;
}

// Abramowitz-Stegun 7.1.26 erf: |err| <= 1.5e-7, branch-free
__device__ inline float erf_approx(float x) {
    float ax = fabsf(x);
    float t = __builtin_amdgcn_rcpf(fmaf(0.3275911f, ax, 1.0f));
    float p = fmaf(1.061405429f, t, -1.453152027f);
    p = fmaf(p, t, 1.421413741f);
    p = fmaf(p, t, -0.284496736f);
    p = fmaf(p, t, 0.254829592f);
    p = p * t;
    float e = __expf(-ax * ax);
    float r = fmaf(-p, e, 1.0f);
    return copysignf(r, x);
}
__device__ inline float gelu_f(float v) {
    return 0.5f * v * (1.0f + erf_approx(v * 0.70710678118654752f));
}

// ---------- kernel 0: query path -> r[b] ; split-bf16 weight prep ----------
__global__ __launch_bounds__(128) void k0_prep(
    const float* __restrict__ xq, const float* __restrict__ wq1, const float* __restrict__ bq1,
    const float* __restrict__ wq2, const float* __restrict__ bq2,
    const float* __restrict__ wqp, const float* __restrict__ bqp,
    const float* __restrict__ wkp,
    const float* __restrict__ wx1, const float* __restrict__ wx2,
    float* __restrict__ r_out, unsigned short* __restrict__ w1h, unsigned short* __restrict__ w1l) {
    __shared__ float buf1[128], buf2[128], buf3[128], buf4[128];
    int t = threadIdx.x;
    int blk = blockIdx.x;
    if (blk < BATCH) {
        int b = blk;
        float xqv = xq[b];
        buf1[t] = gelu_f(fmaf(xqv, wq1[t], bq1[t]));
        __syncthreads();
        float acc = bq2[t];
        for (int j = 0; j < 128; j++) acc = fmaf(buf1[j], wq2[j * 128 + t], acc);
        buf2[t] = acc;
        __syncthreads();
        acc = bqp[t];
        for (int j = 0; j < 128; j++) acc = fmaf(buf2[j], wqp[j * 128 + t], acc);
        buf3[t] = acc;                       // q[b]
        __syncthreads();
        acc = 0.f;
        for (int i = 0; i < 128; i++) acc = fmaf(wkp[t * 128 + i], buf3[i], acc);
        buf4[t] = acc * 0.08838834764831845f; // qt = (wkp @ q) * 128^-0.5
        __syncthreads();
        acc = 0.f;
        for (int i = 0; i < 128; i++) acc = fmaf(wx2[t * 128 + i], buf4[i], acc);
        r_out[b * 128 + t] = acc;            // r = wx2 @ qt  (score[n] = h1g[n] . r[b] + const)
    } else {
        // wx1 [64][128] -> w1h/w1l [n=128][k=64] bf16 hi/lo split
        for (int idx = t; idx < 64 * 128; idx += 128) {
            int k = idx >> 7, n = idx & 127;
            float v = wx1[idx];
            unsigned short hi = f2bf(v);
            float lo = v - bf2f(hi);
            w1h[n * 64 + k] = hi;
            w1l[n * 64 + k] = f2bf(lo);
        }
    }
}

// ---------- kernel 1: per-item GEMM1 (split-bf16 MFMA) + gelu + score dot ----------
// 64 items per block, 256 threads = 4 waves, each wave owns a 32-wide n-slice.
__global__ __launch_bounds__(256) void k1_items(
    const float* __restrict__ x, const unsigned short* __restrict__ w1h,
    const unsigned short* __restrict__ w1l, const float* __restrict__ bx1,
    const float* __restrict__ r_in, float* __restrict__ scores) {
    __shared__ alignas(16) unsigned short lxh[64 * 72];
    __shared__ alignas(16) unsigned short lxl[64 * 72];
    __shared__ float lscore[64];
    int tid = threadIdx.x;
    int wave = tid >> 6, lane = tid & 63;
    int quad = lane >> 4, l15 = lane & 15;
    int tile = blockIdx.x;
    long item0 = (long)tile * 64;
    int b = tile >> 8;                       // 256 tiles per batch

    // resident B fragments (K=64 -> 2 k-steps; 2 n-tiles of 16 per wave)
    short8 bh[2][2], bl[2][2];
    {
        int nb = wave * 32 + l15;
        for (int s = 0; s < 2; s++)
            for (int nt = 0; nt < 2; nt++) {
                int off = (nb + nt * 16) * 64 + s * 32 + quad * 8;
                bh[s][nt] = *(const short8*)(w1h + off);
                bl[s][nt] = *(const short8*)(w1l + off);
            }
    }
    float bias[2], rv[2];
    for (int nt = 0; nt < 2; nt++) {
        int c = wave * 32 + nt * 16 + l15;
        bias[nt] = bx1[c];
        rv[nt] = r_in[b * 128 + c];
    }
    if (tid < 64) lscore[tid] = 0.f;

    // stage x tile [64 rows x 64 cols] fp32 -> hi/lo bf16 in LDS (pad 72)
    const float* xg = x + item0 * 64;
    for (int p = 0; p < 4; p++) {
        int idx = tid + p * 256;
        int row = idx >> 4, c4 = (idx & 15) * 4;
        float4 v = *(const float4*)(xg + row * 64 + c4);
        float vv[4] = {v.x, v.y, v.z, v.w};
        ushort4v hi, lo;
        for (int j = 0; j < 4; j++) {
            unsigned short h = f2bf(vv[j]);
            hi[j] = h;
            lo[j] = f2bf(vv[j] - bf2f(h));
        }
        *(ushort4v*)(lxh + row * 72 + c4) = hi;
        *(ushort4v*)(lxl + row * 72 + c4) = lo;
    }
    __syncthreads();

    f32x4 acc[4][2];
    for (int mt = 0; mt < 4; mt++) for (int nt = 0; nt < 2; nt++) acc[mt][nt] = (f32x4)0.f;

    for (int s = 0; s < 2; s++) {
        int koff = s * 32 + quad * 8;
        short8 ah[4], al[4];
        for (int mt = 0; mt < 4; mt++) {
            int rb = (mt * 16 + l15) * 72 + koff;
            ah[mt] = *(const short8*)(lxh + rb);
            al[mt] = *(const short8*)(lxl + rb);
        }
        for (int mt = 0; mt < 4; mt++)
            for (int nt = 0; nt < 2; nt++) {
                acc[mt][nt] = __builtin_amdgcn_mfma_f32_16x16x32_bf16(al[mt], bh[s][nt], acc[mt][nt], 0, 0, 0);
                acc[mt][nt] = __builtin_amdgcn_mfma_f32_16x16x32_bf16(ah[mt], bl[s][nt], acc[mt][nt], 0, 0, 0);
                acc[mt][nt] = __builtin_amdgcn_mfma_f32_16x16x32_bf16(ah[mt], bh[s][nt], acc[mt][nt], 0, 0, 0);
            }
    }

    // epilogue: bias + gelu + dot with r[b], reduce over the 16-lane quad group
    float pr[4][4];
    for (int mt = 0; mt < 4; mt++) for (int rr = 0; rr < 4; rr++) pr[mt][rr] = 0.f;
    for (int mt = 0; mt < 4; mt++)
        for (int nt = 0; nt < 2; nt++)
            for (int rr = 0; rr < 4; rr++) {
                float g = gelu_f(acc[mt][nt][rr] + bias[nt]);
                pr[mt][rr] = fmaf(g, rv[nt], pr[mt][rr]);
            }
    for (int off = 1; off < 16; off <<= 1)
        for (int mt = 0; mt < 4; mt++)
            for (int rr = 0; rr < 4; rr++)
                pr[mt][rr] += __shfl_xor(pr[mt][rr], off);
    if (l15 == 0)
        for (int mt = 0; mt < 4; mt++)
            for (int rr = 0; rr < 4; rr++)
                atomicAdd(&lscore[mt * 16 + quad * 4 + rr], pr[mt][rr]);
    __syncthreads();
    if (tid < 64) scores[item0 + tid] = lscore[tid];
}

// ---------- kernel 2: sparsemax tau per batch (Michelot fixed point) + zero u ----------
__device__ inline void blockReduce2(float& a, float& c, float* la, float* lc) {
    for (int off = 32; off; off >>= 1) { a += __shfl_down(a, off); c += __shfl_down(c, off); }
    int wid = threadIdx.x >> 6;
    if ((threadIdx.x & 63) == 0) { la[wid] = a; lc[wid] = c; }
    __syncthreads();
    if (threadIdx.x < 64) {
        float x1 = (threadIdx.x < 16) ? la[threadIdx.x] : 0.f;
        float x2 = (threadIdx.x < 16) ? lc[threadIdx.x] : 0.f;
        for (int off = 8; off; off >>= 1) { x1 += __shfl_down(x1, off); x2 += __shfl_down(x2, off); }
        if (threadIdx.x == 0) { la[0] = x1; lc[0] = x2; }
    }
    __syncthreads();
    a = la[0]; c = lc[0];
    __syncthreads();
}

__global__ __launch_bounds__(1024) void k2_tau(const float* __restrict__ scores,
                                               float* __restrict__ tau_out,
                                               float* __restrict__ u) {
    __shared__ float la[16], lc[16];
    int b = blockIdx.x, t = threadIdx.x;
    const float* s = scores + (size_t)b * NITEMS;
    float z[16];
    for (int i = 0; i < 16; i++) z[i] = s[t + i * 1024];
    float sm = 0.f, dummy = 0.f;
    for (int i = 0; i < 16; i++) sm += z[i];
    blockReduce2(sm, dummy, la, lc);
    float tau = (sm - 1.0f) * (1.0f / 16384.0f);     // Michelot iterate 0 (active = all)
    for (int it = 0; it < 24; it++) {
        float ls = 0.f, ct = 0.f;
        for (int i = 0; i < 16; i++)
            if (z[i] > tau) { ls += z[i]; ct += 1.0f; }
        blockReduce2(ls, ct, la, lc);
        tau = (ls - 1.0f) / ct;                       // ct >= 1 always (max > tau)
    }
    if (t == 0) tau_out[b] = tau;
    if (t < 128) u[b * 128 + t] = 0.f;
}

// ---------- kernel 3: gather support items, recompute h in fp32, weighted-sum into u ----------
__global__ __launch_bounds__(256) void k3_support(
    const float* __restrict__ scores, const float* __restrict__ tau_in,
    const float* __restrict__ x,
    const float* __restrict__ wx1, const float* __restrict__ bx1,
    const float* __restrict__ wx2, const float* __restrict__ bx2,
    float* __restrict__ u) {
    __shared__ int lcount;
    __shared__ int lidx[2048];
    __shared__ float lw[2048];
    __shared__ float xr[64];
    __shared__ float h1buf[128];
    int blk = blockIdx.x;
    int b = blk >> 3, chunk = blk & 7;                // 8 chunks of 2048 items per batch
    int t = threadIdx.x;
    if (t == 0) lcount = 0;
    __syncthreads();
    float tau = tau_in[b];
    for (int i = 0; i < 8; i++) {
        int idx = chunk * 2048 + t + i * 256;
        float w = scores[(size_t)b * NITEMS + idx] - tau;
        if (w > 0.f) {
            int pos = atomicAdd(&lcount, 1);
            lidx[pos] = idx; lw[pos] = w;             // cap 2048 == chunk size, cannot overflow
        }
    }
    __syncthreads();
    int cnt = lcount;
    float uacc = 0.f;
    for (int e = 0; e < cnt; e++) {
        int item = lidx[e];
        float w = lw[e];
        if (t < 64) xr[t] = x[((size_t)b * NITEMS + item) * 64 + t];
        __syncthreads();
        if (t < 128) {
            float pre = bx1[t];
            for (int k = 0; k < 64; k++) pre = fmaf(xr[k], wx1[k * 128 + t], pre);
            h1buf[t] = gelu_f(pre);
        }
        __syncthreads();
        if (t < 128) {
            float hv = bx2[t];
            for (int k = 0; k < 128; k++) hv = fmaf(h1buf[k], wx2[k * 128 + t], hv);
            uacc = fmaf(w, hv, uacc);
        }
        __syncthreads();
    }
    if (t < 128) atomicAdd(&u[b * 128 + t], uacc);
}

// ---------- kernel 4: z = u@wvp + bvp ; out = gelu(z@wp1+bp1)@wp2 + bp2 ----------
__global__ __launch_bounds__(128) void k4_head(
    const float* __restrict__ u, const float* __restrict__ wvp, const float* __restrict__ bvp,
    const float* __restrict__ wp1, const float* __restrict__ bp1,
    const float* __restrict__ wp2, const float* __restrict__ bp2,
    float* __restrict__ out) {
    __shared__ float ub[128], zb[128], tb[128];
    int b = blockIdx.x, t = threadIdx.x;
    ub[t] = u[b * 128 + t];
    __syncthreads();
    float z = bvp[t];
    for (int j = 0; j < 128; j++) z = fmaf(ub[j], wvp[j * 128 + t], z);
    zb[t] = z;
    __syncthreads();
    float h = bp1[t];
    for (int j = 0; j < 128; j++) h = fmaf(zb[j], wp1[j * 128 + t], h);
    tb[t] = gelu_f(h);
    __syncthreads();
    if (t < 10) {
        float o = bp2[t];
        for (int j = 0; j < 128; j++) o = fmaf(tb[j], wp2[j * 10 + t], o);
        out[b * 10 + t] = o;
    }
}

// ---------- launch ----------
extern "C" void kernel_launch(void* const* d_in, const int* in_sizes, int n_in,
                              void* d_out, int out_size, void* d_ws, size_t ws_size,
                              hipStream_t stream) {
    const float* x_items = (const float*)d_in[0];
    const float* x_query = (const float*)d_in[1];
    const float* wx1 = (const float*)d_in[2];
    const float* bx1 = (const float*)d_in[3];
    const float* wx2 = (const float*)d_in[4];
    const float* bx2 = (const float*)d_in[5];
    const float* wq1 = (const float*)d_in[6];
    const float* bq1 = (const float*)d_in[7];
    const float* wq2 = (const float*)d_in[8];
    const float* bq2 = (const float*)d_in[9];
    const float* wqp = (const float*)d_in[10];
    const float* bqp = (const float*)d_in[11];
    const float* wkp = (const float*)d_in[12];
    // d_in[13] = bkp: dropped (sparsemax shift invariance)
    const float* wvp = (const float*)d_in[14];
    const float* bvp = (const float*)d_in[15];
    const float* wp1 = (const float*)d_in[16];
    const float* bp1 = (const float*)d_in[17];
    const float* wp2 = (const float*)d_in[18];
    const float* bp2 = (const float*)d_in[19];
    float* out = (float*)d_out;

    char* ws = (char*)d_ws;
    float* r_buf        = (float*)(ws);                                   // 32*128*4   = 16 KB
    unsigned short* w1h = (unsigned short*)(ws + 16384);                  // 128*64*2   = 16 KB
    unsigned short* w1l = (unsigned short*)(ws + 32768);                  // 16 KB
    float* scores       = (float*)(ws + 49152);                           // 32*16384*4 = 2 MB
    float* tau          = (float*)(ws + 49152 + 2097152);                 // 128 B
    float* u            = (float*)(ws + 49152 + 2097152 + 256);           // 16 KB

    k0_prep<<<33, 128, 0, stream>>>(x_query, wq1, bq1, wq2, bq2, wqp, bqp, wkp,
                                    wx1, wx2, r_buf, w1h, w1l);
    k1_items<<<(BATCH * NITEMS) / 64, 256, 0, stream>>>(x_items, w1h, w1l, bx1, r_buf, scores);
    k2_tau<<<BATCH, 1024, 0, stream>>>(scores, tau, u);
    k3_support<<<BATCH * 8, 256, 0, stream>>>(scores, tau, x_items, wx1, bx1, wx2, bx2, u);
    k4_head<<<BATCH, 128, 0, stream>>>(u, wvp, bvp, wp1, bp1, wp2, bp2, out);
}

// Round 2
// 346.391 us; speedup vs baseline: 1.7284x; 1.7284x over previous
//
#include <hip/hip_runtime.h>
#include <hip/hip_bf16.h>
#include <cstdint>

#define BATCH 32
#define NITEMS 16384
#define DEMB 128
#define IDIM 64

typedef short short8 __attribute__((ext_vector_type(8)));
typedef float f32x4 __attribute__((ext_vector_type(4)));
typedef unsigned short ushort4v __attribute__((ext_vector_type(4)));

// ---------- helpers ----------
__device__ inline unsigned short f2bf(float f) {
    union { float f; unsigned int u; } v; v.f = f;
    unsigned int u = v.u;
    unsigned int r = (u + 0x7FFFu + ((u >> 16) & 1u)) >> 16;   // RNE, data is finite
    return (unsigned short)r;
}
__device__ inline float bf2f(unsigned short h) {
    union { unsigned int u; float f; } v; v.u = ((unsigned int)h) << 16;
    return v.f;
}

// Abramowitz-Stegun 7.1.26 erf: |err| <= 1.5e-7, branch-free
__device__ inline float erf_approx(float x) {
    float ax = fabsf(x);
    float t = __builtin_amdgcn_rcpf(fmaf(0.3275911f, ax, 1.0f));
    float p = fmaf(1.061405429f, t, -1.453152027f);
    p = fmaf(p, t, 1.421413741f);
    p = fmaf(p, t, -0.284496736f);
    p = fmaf(p, t, 0.254829592f);
    p = p * t;
    float e = __expf(-ax * ax);
    float r = fmaf(-p, e, 1.0f);
    return copysignf(r, x);
}
__device__ inline float gelu_f(float v) {
    return 0.5f * v * (1.0f + erf_approx(v * 0.70710678118654752f));
}

// ---------- kernel 0: query path -> r[b] ; split-bf16 weight prep ----------
__global__ __launch_bounds__(128) void k0_prep(
    const float* __restrict__ xq, const float* __restrict__ wq1, const float* __restrict__ bq1,
    const float* __restrict__ wq2, const float* __restrict__ bq2,
    const float* __restrict__ wqp, const float* __restrict__ bqp,
    const float* __restrict__ wkp,
    const float* __restrict__ wx1, const float* __restrict__ wx2,
    float* __restrict__ r_out, unsigned short* __restrict__ w1h, unsigned short* __restrict__ w1l) {
    __shared__ float buf1[128], buf2[128], buf3[128], buf4[128];
    int t = threadIdx.x;
    int blk = blockIdx.x;
    if (blk < BATCH) {
        int b = blk;
        float xqv = xq[b];
        buf1[t] = gelu_f(fmaf(xqv, wq1[t], bq1[t]));
        __syncthreads();
        float acc = bq2[t];
        for (int j = 0; j < 128; j++) acc = fmaf(buf1[j], wq2[j * 128 + t], acc);
        buf2[t] = acc;
        __syncthreads();
        acc = bqp[t];
        for (int j = 0; j < 128; j++) acc = fmaf(buf2[j], wqp[j * 128 + t], acc);
        buf3[t] = acc;                       // q[b]
        __syncthreads();
        acc = 0.f;
        for (int i = 0; i < 128; i++) acc = fmaf(wkp[t * 128 + i], buf3[i], acc);
        buf4[t] = acc * 0.08838834764831845f; // qt = (wkp @ q) * 128^-0.5
        __syncthreads();
        acc = 0.f;
        for (int i = 0; i < 128; i++) acc = fmaf(wx2[t * 128 + i], buf4[i], acc);
        r_out[b * 128 + t] = acc;            // r = wx2 @ qt  (score[n] = h1g[n] . r[b] + const)
    } else {
        // wx1 [64][128] -> w1h/w1l [n=128][k=64] bf16 hi/lo split
        for (int idx = t; idx < 64 * 128; idx += 128) {
            int k = idx >> 7, n = idx & 127;
            float v = wx1[idx];
            unsigned short hi = f2bf(v);
            float lo = v - bf2f(hi);
            w1h[n * 64 + k] = hi;
            w1l[n * 64 + k] = f2bf(lo);
        }
    }
}

// ---------- kernel 1: per-item GEMM1 (split-bf16 MFMA) + gelu + score dot ----------
// 64 items per block, 256 threads = 4 waves, each wave owns a 32-wide n-slice.
__global__ __launch_bounds__(256) void k1_items(
    const float* __restrict__ x, const unsigned short* __restrict__ w1h,
    const unsigned short* __restrict__ w1l, const float* __restrict__ bx1,
    const float* __restrict__ r_in, float* __restrict__ scores) {
    __shared__ alignas(16) unsigned short lxh[64 * 72];
    __shared__ alignas(16) unsigned short lxl[64 * 72];
    __shared__ float lscore[64];
    int tid = threadIdx.x;
    int wave = tid >> 6, lane = tid & 63;
    int quad = lane >> 4, l15 = lane & 15;
    int tile = blockIdx.x;
    long item0 = (long)tile * 64;
    int b = tile >> 8;                       // 256 tiles per batch

    // resident B fragments (K=64 -> 2 k-steps; 2 n-tiles of 16 per wave)
    short8 bh[2][2], bl[2][2];
    {
        int nb = wave * 32 + l15;
        for (int s = 0; s < 2; s++)
            for (int nt = 0; nt < 2; nt++) {
                int off = (nb + nt * 16) * 64 + s * 32 + quad * 8;
                bh[s][nt] = *(const short8*)(w1h + off);
                bl[s][nt] = *(const short8*)(w1l + off);
            }
    }
    float bias[2], rv[2];
    for (int nt = 0; nt < 2; nt++) {
        int c = wave * 32 + nt * 16 + l15;
        bias[nt] = bx1[c];
        rv[nt] = r_in[b * 128 + c];
    }
    if (tid < 64) lscore[tid] = 0.f;

    // stage x tile [64 rows x 64 cols] fp32 -> hi/lo bf16 in LDS (pad 72)
    const float* xg = x + item0 * 64;
    for (int p = 0; p < 4; p++) {
        int idx = tid + p * 256;
        int row = idx >> 4, c4 = (idx & 15) * 4;
        float4 v = *(const float4*)(xg + row * 64 + c4);
        float vv[4] = {v.x, v.y, v.z, v.w};
        ushort4v hi, lo;
        for (int j = 0; j < 4; j++) {
            unsigned short h = f2bf(vv[j]);
            hi[j] = h;
            lo[j] = f2bf(vv[j] - bf2f(h));
        }
        *(ushort4v*)(lxh + row * 72 + c4) = hi;
        *(ushort4v*)(lxl + row * 72 + c4) = lo;
    }
    __syncthreads();

    f32x4 acc[4][2];
    for (int mt = 0; mt < 4; mt++) for (int nt = 0; nt < 2; nt++) acc[mt][nt] = (f32x4)0.f;

    for (int s = 0; s < 2; s++) {
        int koff = s * 32 + quad * 8;
        short8 ah[4], al[4];
        for (int mt = 0; mt < 4; mt++) {
            int rb = (mt * 16 + l15) * 72 + koff;
            ah[mt] = *(const short8*)(lxh + rb);
            al[mt] = *(const short8*)(lxl + rb);
        }
        for (int mt = 0; mt < 4; mt++)
            for (int nt = 0; nt < 2; nt++) {
                acc[mt][nt] = __builtin_amdgcn_mfma_f32_16x16x32_bf16(al[mt], bh[s][nt], acc[mt][nt], 0, 0, 0);
                acc[mt][nt] = __builtin_amdgcn_mfma_f32_16x16x32_bf16(ah[mt], bl[s][nt], acc[mt][nt], 0, 0, 0);
                acc[mt][nt] = __builtin_amdgcn_mfma_f32_16x16x32_bf16(ah[mt], bh[s][nt], acc[mt][nt], 0, 0, 0);
            }
    }

    // epilogue: bias + gelu + dot with r[b], reduce over the 16-lane quad group
    float pr[4][4];
    for (int mt = 0; mt < 4; mt++) for (int rr = 0; rr < 4; rr++) pr[mt][rr] = 0.f;
    for (int mt = 0; mt < 4; mt++)
        for (int nt = 0; nt < 2; nt++)
            for (int rr = 0; rr < 4; rr++) {
                float g = gelu_f(acc[mt][nt][rr] + bias[nt]);
                pr[mt][rr] = fmaf(g, rv[nt], pr[mt][rr]);
            }
    for (int off = 1; off < 16; off <<= 1)
        for (int mt = 0; mt < 4; mt++)
            for (int rr = 0; rr < 4; rr++)
                pr[mt][rr] += __shfl_xor(pr[mt][rr], off);
    if (l15 == 0)
        for (int mt = 0; mt < 4; mt++)
            for (int rr = 0; rr < 4; rr++)
                atomicAdd(&lscore[mt * 16 + quad * 4 + rr], pr[mt][rr]);
    __syncthreads();
    if (tid < 64) scores[item0 + tid] = lscore[tid];
}

// ---------- kernel 2: sparsemax tau per batch (Michelot fixed point) + zero u ----------
__device__ inline void blockReduce2(float& a, float& c, float* la, float* lc) {
    for (int off = 32; off; off >>= 1) { a += __shfl_down(a, off); c += __shfl_down(c, off); }
    int wid = threadIdx.x >> 6;
    if ((threadIdx.x & 63) == 0) { la[wid] = a; lc[wid] = c; }
    __syncthreads();
    if (threadIdx.x < 64) {
        float x1 = (threadIdx.x < 16) ? la[threadIdx.x] : 0.f;
        float x2 = (threadIdx.x < 16) ? lc[threadIdx.x] : 0.f;
        for (int off = 8; off; off >>= 1) { x1 += __shfl_down(x1, off); x2 += __shfl_down(x2, off); }
        if (threadIdx.x == 0) { la[0] = x1; lc[0] = x2; }
    }
    __syncthreads();
    a = la[0]; c = lc[0];
    __syncthreads();
}

__global__ __launch_bounds__(1024) void k2_tau(const float* __restrict__ scores,
                                               float* __restrict__ tau_out,
                                               float* __restrict__ u) {
    __shared__ float la[16], lc[16];
    int b = blockIdx.x, t = threadIdx.x;
    const float* s = scores + (size_t)b * NITEMS;
    float z[16];
    for (int i = 0; i < 16; i++) z[i] = s[t + i * 1024];
    float sm = 0.f, dummy = 0.f;
    for (int i = 0; i < 16; i++) sm += z[i];
    blockReduce2(sm, dummy, la, lc);
    float tau = (sm - 1.0f) * (1.0f / 16384.0f);     // Michelot iterate 0 (active = all)
    for (int it = 0; it < 24; it++) {
        float ls = 0.f, ct = 0.f;
        for (int i = 0; i < 16; i++)
            if (z[i] > tau) { ls += z[i]; ct += 1.0f; }
        blockReduce2(ls, ct, la, lc);
        tau = (ls - 1.0f) / ct;                       // ct >= 1 always (max > tau)
    }
    if (t == 0) tau_out[b] = tau;
    if (t < 128) u[b * 128 + t] = 0.f;
}

// ---------- kernel 3: one wave per support item, fp32 recompute, shfl broadcasts ----------
// 32 blocks per batch x 4 waves = 128 waves/batch; wave w scans items [w*128, w*128+128).
// No __syncthreads in the hot loop; per-item work is wave-local (shuffles + L1-cached weights).
__global__ __launch_bounds__(256) void k3_support(
    const float* __restrict__ scores, const float* __restrict__ tau_in,
    const float* __restrict__ x,
    const float* __restrict__ wx1, const float* __restrict__ bx1,
    const float* __restrict__ wx2, const float* __restrict__ bx2,
    float* __restrict__ u) {
    __shared__ float red[4][128];
    int blk = blockIdx.x;
    int b = blk >> 5;                 // 32 blocks per batch
    int sub = blk & 31;
    int wave = threadIdx.x >> 6, lane = threadIdx.x & 63;
    int wslot = sub * 4 + wave;       // 0..127 within batch
    int base = wslot * 128;           // this wave's 128-item slice
    float tau = tau_in[b];
    int t0 = lane, t1 = lane + 64;
    float bb0 = bx1[t0], bb1 = bx1[t1];
    float cc0 = bx2[t0], cc1 = bx2[t1];
    float u0 = 0.f, u1 = 0.f;
    const float* srow = scores + (size_t)b * NITEMS + base;
    for (int half = 0; half < 2; half++) {
        float sv = srow[half * 64 + lane] - tau;
        unsigned long long mask = __ballot(sv > 0.f);
        while (mask) {
            int src = __ffsll((long long)mask) - 1;
            mask &= mask - 1;
            float wgt = __shfl(sv, src);
            int item = base + half * 64 + src;
            const float* xr = x + ((size_t)b * NITEMS + item) * 64;
            float xv = xr[lane];
            // layer 1: lane computes h1 dims t0, t1; x broadcast via shfl
            float p0 = bb0, p1 = bb1;
            for (int k = 0; k < 64; k++) {
                float xk = __shfl(xv, k);
                p0 = fmaf(xk, wx1[k * 128 + t0], p0);
                p1 = fmaf(xk, wx1[k * 128 + t1], p1);
            }
            float h0 = gelu_f(p0), h1 = gelu_f(p1);
            // layer 2: h broadcast via shfl (j ascending: 0..63 from h0, 64..127 from h1)
            float a0 = cc0, a1 = cc1;
            for (int j = 0; j < 64; j++) {
                float hj = __shfl(h0, j);
                a0 = fmaf(hj, wx2[j * 128 + t0], a0);
                a1 = fmaf(hj, wx2[j * 128 + t1], a1);
            }
            for (int j = 0; j < 64; j++) {
                float hj = __shfl(h1, j);
                a0 = fmaf(hj, wx2[(j + 64) * 128 + t0], a0);
                a1 = fmaf(hj, wx2[(j + 64) * 128 + t1], a1);
            }
            u0 = fmaf(wgt, a0, u0);
            u1 = fmaf(wgt, a1, u1);
        }
    }
    red[wave][t0] = u0;
    red[wave][t1] = u1;
    __syncthreads();
    if (threadIdx.x < 128) {
        float s = red[0][threadIdx.x] + red[1][threadIdx.x] +
                  red[2][threadIdx.x] + red[3][threadIdx.x];
        atomicAdd(&u[b * 128 + threadIdx.x], s);
    }
}

// ---------- kernel 4: z = u@wvp + bvp ; out = gelu(z@wp1+bp1)@wp2 + bp2 ----------
__global__ __launch_bounds__(128) void k4_head(
    const float* __restrict__ u, const float* __restrict__ wvp, const float* __restrict__ bvp,
    const float* __restrict__ wp1, const float* __restrict__ bp1,
    const float* __restrict__ wp2, const float* __restrict__ bp2,
    float* __restrict__ out) {
    __shared__ float ub[128], zb[128], tb[128];
    int b = blockIdx.x, t = threadIdx.x;
    ub[t] = u[b * 128 + t];
    __syncthreads();
    float z = bvp[t];
    for (int j = 0; j < 128; j++) z = fmaf(ub[j], wvp[j * 128 + t], z);
    zb[t] = z;
    __syncthreads();
    float h = bp1[t];
    for (int j = 0; j < 128; j++) h = fmaf(zb[j], wp1[j * 128 + t], h);
    tb[t] = gelu_f(h);
    __syncthreads();
    if (t < 10) {
        float o = bp2[t];
        for (int j = 0; j < 128; j++) o = fmaf(tb[j], wp2[j * 10 + t], o);
        out[b * 10 + t] = o;
    }
}

// ---------- launch ----------
extern "C" void kernel_launch(void* const* d_in, const int* in_sizes, int n_in,
                              void* d_out, int out_size, void* d_ws, size_t ws_size,
                              hipStream_t stream) {
    const float* x_items = (const float*)d_in[0];
    const float* x_query = (const float*)d_in[1];
    const float* wx1 = (const float*)d_in[2];
    const float* bx1 = (const float*)d_in[3];
    const float* wx2 = (const float*)d_in[4];
    const float* bx2 = (const float*)d_in[5];
    const float* wq1 = (const float*)d_in[6];
    const float* bq1 = (const float*)d_in[7];
    const float* wq2 = (const float*)d_in[8];
    const float* bq2 = (const float*)d_in[9];
    const float* wqp = (const float*)d_in[10];
    const float* bqp = (const float*)d_in[11];
    const float* wkp = (const float*)d_in[12];
    // d_in[13] = bkp: dropped (sparsemax shift invariance)
    const float* wvp = (const float*)d_in[14];
    const float* bvp = (const float*)d_in[15];
    const float* wp1 = (const float*)d_in[16];
    const float* bp1 = (const float*)d_in[17];
    const float* wp2 = (const float*)d_in[18];
    const float* bp2 = (const float*)d_in[19];
    float* out = (float*)d_out;

    char* ws = (char*)d_ws;
    float* r_buf        = (float*)(ws);                                   // 32*128*4   = 16 KB
    unsigned short* w1h = (unsigned short*)(ws + 16384);                  // 128*64*2   = 16 KB
    unsigned short* w1l = (unsigned short*)(ws + 32768);                  // 16 KB
    float* scores       = (float*)(ws + 49152);                           // 32*16384*4 = 2 MB
    float* tau          = (float*)(ws + 49152 + 2097152);                 // 128 B
    float* u            = (float*)(ws + 49152 + 2097152 + 256);           // 16 KB

    k0_prep<<<33, 128, 0, stream>>>(x_query, wq1, bq1, wq2, bq2, wqp, bqp, wkp,
                                    wx1, wx2, r_buf, w1h, w1l);
    k1_items<<<(BATCH * NITEMS) / 64, 256, 0, stream>>>(x_items, w1h, w1l, bx1, r_buf, scores);
    k2_tau<<<BATCH, 1024, 0, stream>>>(scores, tau, u);
    k3_support<<<BATCH * 32, 256, 0, stream>>>(scores, tau, x_items, wx1, bx1, wx2, bx2, u);
    k4_head<<<BATCH, 128, 0, stream>>>(u, wvp, bvp, wp1, bp1, wp2, bp2, out);
}

// Round 3
// 338.281 us; speedup vs baseline: 1.7698x; 1.0240x over previous
//
#include <hip/hip_runtime.h>
#include <hip/hip_bf16.h>
#include <cstdint>

#define BATCH 32
#define NITEMS 16384
#define DEMB 128
#define IDIM 64

typedef short short8 __attribute__((ext_vector_type(8)));
typedef float f32x4 __attribute__((ext_vector_type(4)));

// ---------- helpers ----------
__device__ inline unsigned short f2bf(float f) {
    union { float f; unsigned int u; } v; v.f = f;
    unsigned int u = v.u;
    unsigned int r = (u + 0x7FFFu + ((u >> 16) & 1u)) >> 16;   // RNE, data is finite
    return (unsigned short)r;
}
__device__ inline float bf2f(unsigned short h) {
    union { unsigned int u; float f; } v; v.u = ((unsigned int)h) << 16;
    return v.f;
}

// Abramowitz-Stegun 7.1.26 erf: |err| <= 1.5e-7, branch-free
__device__ inline float erf_approx(float x) {
    float ax = fabsf(x);
    float t = __builtin_amdgcn_rcpf(fmaf(0.3275911f, ax, 1.0f));
    float p = fmaf(1.061405429f, t, -1.453152027f);
    p = fmaf(p, t, 1.421413741f);
    p = fmaf(p, t, -0.284496736f);
    p = fmaf(p, t, 0.254829592f);
    p = p * t;
    float e = __expf(-ax * ax);
    float r = fmaf(-p, e, 1.0f);
    return copysignf(r, x);
}
__device__ inline float gelu_f(float v) {
    return 0.5f * v * (1.0f + erf_approx(v * 0.70710678118654752f));
}

// ---------- kernel 0: query path -> r[b] ; split-bf16 weight prep ----------
__global__ __launch_bounds__(128) void k0_prep(
    const float* __restrict__ xq, const float* __restrict__ wq1, const float* __restrict__ bq1,
    const float* __restrict__ wq2, const float* __restrict__ bq2,
    const float* __restrict__ wqp, const float* __restrict__ bqp,
    const float* __restrict__ wkp,
    const float* __restrict__ wx1, const float* __restrict__ wx2,
    float* __restrict__ r_out, unsigned short* __restrict__ w1h, unsigned short* __restrict__ w1l) {
    __shared__ float buf1[128], buf2[128], buf3[128], buf4[128];
    int t = threadIdx.x;
    int blk = blockIdx.x;
    if (blk < BATCH) {
        int b = blk;
        float xqv = xq[b];
        buf1[t] = gelu_f(fmaf(xqv, wq1[t], bq1[t]));
        __syncthreads();
        float acc = bq2[t];
        for (int j = 0; j < 128; j++) acc = fmaf(buf1[j], wq2[j * 128 + t], acc);
        buf2[t] = acc;
        __syncthreads();
        acc = bqp[t];
        for (int j = 0; j < 128; j++) acc = fmaf(buf2[j], wqp[j * 128 + t], acc);
        buf3[t] = acc;                       // q[b]
        __syncthreads();
        acc = 0.f;
        for (int i = 0; i < 128; i++) acc = fmaf(wkp[t * 128 + i], buf3[i], acc);
        buf4[t] = acc * 0.08838834764831845f; // qt = (wkp @ q) * 128^-0.5
        __syncthreads();
        acc = 0.f;
        for (int i = 0; i < 128; i++) acc = fmaf(wx2[t * 128 + i], buf4[i], acc);
        r_out[b * 128 + t] = acc;            // r = wx2 @ qt  (score[n] = h1g[n] . r[b] + const)
    } else {
        // wx1 [64][128] -> w1h/w1l [n=128][k=64] bf16 hi/lo split
        for (int idx = t; idx < 64 * 128; idx += 128) {
            int k = idx >> 7, n = idx & 127;
            float v = wx1[idx];
            unsigned short hi = f2bf(v);
            float lo = v - bf2f(hi);
            w1h[n * 64 + k] = hi;
            w1l[n * 64 + k] = f2bf(lo);
        }
    }
}

// ---------- kernel 1: per-item GEMM1 (split-bf16 MFMA) + gelu + score dot ----------
// 64 items per block, 256 threads = 4 waves, each wave owns a 32-wide n-slice.
__global__ __launch_bounds__(256) void k1_items(
    const float* __restrict__ x, const unsigned short* __restrict__ w1h,
    const unsigned short* __restrict__ w1l, const float* __restrict__ bx1,
    const float* __restrict__ r_in, float* __restrict__ scores) {
    __shared__ alignas(16) unsigned short lxh[64 * 72];
    __shared__ alignas(16) unsigned short lxl[64 * 72];
    __shared__ float red[4][64];
    int tid = threadIdx.x;
    int wave = tid >> 6, lane = tid & 63;
    int quad = lane >> 4, l15 = lane & 15;
    int tile = blockIdx.x;
    long item0 = (long)tile * 64;
    int b = tile >> 8;                       // 256 tiles per batch

    // resident B fragments (K=64 -> 2 k-steps; 2 n-tiles of 16 per wave)
    short8 bh[2][2], bl[2][2];
    {
        int nb = wave * 32 + l15;
        for (int s = 0; s < 2; s++)
            for (int nt = 0; nt < 2; nt++) {
                int off = (nb + nt * 16) * 64 + s * 32 + quad * 8;
                bh[s][nt] = *(const short8*)(w1h + off);
                bl[s][nt] = *(const short8*)(w1l + off);
            }
    }
    float bias[2], rv[2];
    for (int nt = 0; nt < 2; nt++) {
        int c = wave * 32 + nt * 16 + l15;
        bias[nt] = bx1[c];
        rv[nt] = r_in[b * 128 + c];
    }

    // stage x tile [64 rows x 64 cols]: trunc hi/lo bf16 split via v_perm packing
    const float* xg = x + item0 * 64;
    for (int p = 0; p < 4; p++) {
        int idx = tid + p * 256;
        int row = idx >> 4, c4 = (idx & 15) * 4;
        float4 v = *(const float4*)(xg + row * 64 + c4);
        unsigned int ux = __float_as_uint(v.x), uy = __float_as_uint(v.y);
        unsigned int uz = __float_as_uint(v.z), uw = __float_as_uint(v.w);
        unsigned int hi01 = __builtin_amdgcn_perm(uy, ux, 0x07060302u);
        unsigned int hi23 = __builtin_amdgcn_perm(uw, uz, 0x07060302u);
        float lx = v.x - __uint_as_float(ux & 0xFFFF0000u);
        float ly = v.y - __uint_as_float(uy & 0xFFFF0000u);
        float lz = v.z - __uint_as_float(uz & 0xFFFF0000u);
        float lw = v.w - __uint_as_float(uw & 0xFFFF0000u);
        unsigned int lo01 = __builtin_amdgcn_perm(__float_as_uint(ly), __float_as_uint(lx), 0x07060302u);
        unsigned int lo23 = __builtin_amdgcn_perm(__float_as_uint(lw), __float_as_uint(lz), 0x07060302u);
        *(uint2*)(lxh + row * 72 + c4) = make_uint2(hi01, hi23);
        *(uint2*)(lxl + row * 72 + c4) = make_uint2(lo01, lo23);
    }
    __syncthreads();

    f32x4 acc[4][2];
    for (int mt = 0; mt < 4; mt++) for (int nt = 0; nt < 2; nt++) acc[mt][nt] = (f32x4)0.f;

    for (int s = 0; s < 2; s++) {
        int koff = s * 32 + quad * 8;
        short8 ah[4], al[4];
        for (int mt = 0; mt < 4; mt++) {
            int rb = (mt * 16 + l15) * 72 + koff;
            ah[mt] = *(const short8*)(lxh + rb);
            al[mt] = *(const short8*)(lxl + rb);
        }
        for (int mt = 0; mt < 4; mt++)
            for (int nt = 0; nt < 2; nt++) {
                acc[mt][nt] = __builtin_amdgcn_mfma_f32_16x16x32_bf16(al[mt], bh[s][nt], acc[mt][nt], 0, 0, 0);
                acc[mt][nt] = __builtin_amdgcn_mfma_f32_16x16x32_bf16(ah[mt], bl[s][nt], acc[mt][nt], 0, 0, 0);
                acc[mt][nt] = __builtin_amdgcn_mfma_f32_16x16x32_bf16(ah[mt], bh[s][nt], acc[mt][nt], 0, 0, 0);
            }
    }

    // epilogue: bias + gelu + dot with r[b], reduce over the 16-lane quad group
    float pr[4][4];
    for (int mt = 0; mt < 4; mt++) for (int rr = 0; rr < 4; rr++) pr[mt][rr] = 0.f;
    for (int mt = 0; mt < 4; mt++)
        for (int nt = 0; nt < 2; nt++)
            for (int rr = 0; rr < 4; rr++) {
                float g = gelu_f(acc[mt][nt][rr] + bias[nt]);
                pr[mt][rr] = fmaf(g, rv[nt], pr[mt][rr]);
            }
    for (int off = 1; off < 16; off <<= 1)
        for (int mt = 0; mt < 4; mt++)
            for (int rr = 0; rr < 4; rr++)
                pr[mt][rr] += __shfl_xor(pr[mt][rr], off);
    if (l15 == 0)
        for (int mt = 0; mt < 4; mt++)
            for (int rr = 0; rr < 4; rr++)
                red[wave][mt * 16 + quad * 4 + rr] = pr[mt][rr];
    __syncthreads();
    if (tid < 64)
        scores[item0 + tid] = red[0][tid] + red[1][tid] + red[2][tid] + red[3][tid];
}

// ---------- kernel 2: sparsemax tau per batch (Michelot fixed point) + zero u ----------
// 1 barrier per iteration: wave-level xor reduce -> ping-pong LDS partials ->
// every thread sums the 16 wave-partials itself (broadcast reads, no 2nd barrier).
__global__ __launch_bounds__(1024) void k2_tau(const float* __restrict__ scores,
                                               float* __restrict__ tau_out,
                                               float* __restrict__ u) {
    __shared__ float la[2][16], lc[2][16];
    int b = blockIdx.x, t = threadIdx.x;
    int wid = t >> 6, lane = t & 63;
    const float* s = scores + (size_t)b * NITEMS;
    float z[16];
    for (int i = 0; i < 16; i++) z[i] = s[t + i * 1024];
    // init (acts as iteration -1, buffer 1): active = all
    float sm = 0.f;
    for (int i = 0; i < 16; i++) sm += z[i];
    for (int off = 32; off; off >>= 1) sm += __shfl_xor(sm, off);
    if (lane == 0) la[1][wid] = sm;
    __syncthreads();
    float tot = 0.f;
    for (int i = 0; i < 16; i++) tot += la[1][i];
    float tau = (tot - 1.0f) * (1.0f / 16384.0f);
    for (int it = 0; it < 20; it++) {
        int pb = it & 1;
        float ls = 0.f, ct = 0.f;
        for (int i = 0; i < 16; i++) {
            bool a = z[i] > tau;
            ls += a ? z[i] : 0.f;
            ct += a ? 1.f : 0.f;
        }
        for (int off = 32; off; off >>= 1) {
            ls += __shfl_xor(ls, off);
            ct += __shfl_xor(ct, off);
        }
        if (lane == 0) { la[pb][wid] = ls; lc[pb][wid] = ct; }
        __syncthreads();
        float tls = 0.f, tct = 0.f;
        for (int i = 0; i < 16; i++) { tls += la[pb][i]; tct += lc[pb][i]; }
        tau = (tls - 1.0f) / tct;            // ct >= 1 always (max > tau)
    }
    if (t == 0) tau_out[b] = tau;
    if (t < 128) u[b * 128 + t] = 0.f;
}

// ---------- kernel 3: one wave per support item, fp32 recompute, shfl broadcasts ----------
__global__ __launch_bounds__(256) void k3_support(
    const float* __restrict__ scores, const float* __restrict__ tau_in,
    const float* __restrict__ x,
    const float* __restrict__ wx1, const float* __restrict__ bx1,
    const float* __restrict__ wx2, const float* __restrict__ bx2,
    float* __restrict__ u) {
    __shared__ float red[4][128];
    int blk = blockIdx.x;
    int b = blk >> 5;                 // 32 blocks per batch
    int sub = blk & 31;
    int wave = threadIdx.x >> 6, lane = threadIdx.x & 63;
    int wslot = sub * 4 + wave;       // 0..127 within batch
    int base = wslot * 128;           // this wave's 128-item slice
    float tau = tau_in[b];
    int t0 = lane, t1 = lane + 64;
    float bb0 = bx1[t0], bb1 = bx1[t1];
    float cc0 = bx2[t0], cc1 = bx2[t1];
    float u0 = 0.f, u1 = 0.f;
    const float* srow = scores + (size_t)b * NITEMS + base;
    for (int half = 0; half < 2; half++) {
        float sv = srow[half * 64 + lane] - tau;
        unsigned long long mask = __ballot(sv > 0.f);
        while (mask) {
            int src = __ffsll((long long)mask) - 1;
            mask &= mask - 1;
            float wgt = __shfl(sv, src);
            int item = base + half * 64 + src;
            const float* xr = x + ((size_t)b * NITEMS + item) * 64;
            float xv = xr[lane];
            float p0 = bb0, p1 = bb1;
            for (int k = 0; k < 64; k++) {
                float xk = __shfl(xv, k);
                p0 = fmaf(xk, wx1[k * 128 + t0], p0);
                p1 = fmaf(xk, wx1[k * 128 + t1], p1);
            }
            float h0 = gelu_f(p0), h1 = gelu_f(p1);
            float a0 = cc0, a1 = cc1;
            for (int j = 0; j < 64; j++) {
                float hj = __shfl(h0, j);
                a0 = fmaf(hj, wx2[j * 128 + t0], a0);
                a1 = fmaf(hj, wx2[j * 128 + t1], a1);
            }
            for (int j = 0; j < 64; j++) {
                float hj = __shfl(h1, j);
                a0 = fmaf(hj, wx2[(j + 64) * 128 + t0], a0);
                a1 = fmaf(hj, wx2[(j + 64) * 128 + t1], a1);
            }
            u0 = fmaf(wgt, a0, u0);
            u1 = fmaf(wgt, a1, u1);
        }
    }
    red[wave][t0] = u0;
    red[wave][t1] = u1;
    __syncthreads();
    if (threadIdx.x < 128) {
        float s = red[0][threadIdx.x] + red[1][threadIdx.x] +
                  red[2][threadIdx.x] + red[3][threadIdx.x];
        atomicAdd(&u[b * 128 + threadIdx.x], s);
    }
}

// ---------- kernel 4: z = u@wvp + bvp ; out = gelu(z@wp1+bp1)@wp2 + bp2 ----------
__global__ __launch_bounds__(128) void k4_head(
    const float* __restrict__ u, const float* __restrict__ wvp, const float* __restrict__ bvp,
    const float* __restrict__ wp1, const float* __restrict__ bp1,
    const float* __restrict__ wp2, const float* __restrict__ bp2,
    float* __restrict__ out) {
    __shared__ float ub[128], zb[128], tb[128];
    int b = blockIdx.x, t = threadIdx.x;
    ub[t] = u[b * 128 + t];
    __syncthreads();
    float z = bvp[t];
    for (int j = 0; j < 128; j++) z = fmaf(ub[j], wvp[j * 128 + t], z);
    zb[t] = z;
    __syncthreads();
    float h = bp1[t];
    for (int j = 0; j < 128; j++) h = fmaf(zb[j], wp1[j * 128 + t], h);
    tb[t] = gelu_f(h);
    __syncthreads();
    if (t < 10) {
        float o = bp2[t];
        for (int j = 0; j < 128; j++) o = fmaf(tb[j], wp2[j * 10 + t], o);
        out[b * 10 + t] = o;
    }
}

// ---------- launch ----------
extern "C" void kernel_launch(void* const* d_in, const int* in_sizes, int n_in,
                              void* d_out, int out_size, void* d_ws, size_t ws_size,
                              hipStream_t stream) {
    const float* x_items = (const float*)d_in[0];
    const float* x_query = (const float*)d_in[1];
    const float* wx1 = (const float*)d_in[2];
    const float* bx1 = (const float*)d_in[3];
    const float* wx2 = (const float*)d_in[4];
    const float* bx2 = (const float*)d_in[5];
    const float* wq1 = (const float*)d_in[6];
    const float* bq1 = (const float*)d_in[7];
    const float* wq2 = (const float*)d_in[8];
    const float* bq2 = (const float*)d_in[9];
    const float* wqp = (const float*)d_in[10];
    const float* bqp = (const float*)d_in[11];
    const float* wkp = (const float*)d_in[12];
    // d_in[13] = bkp: dropped (sparsemax shift invariance)
    const float* wvp = (const float*)d_in[14];
    const float* bvp = (const float*)d_in[15];
    const float* wp1 = (const float*)d_in[16];
    const float* bp1 = (const float*)d_in[17];
    const float* wp2 = (const float*)d_in[18];
    const float* bp2 = (const float*)d_in[19];
    float* out = (float*)d_out;

    char* ws = (char*)d_ws;
    float* r_buf        = (float*)(ws);                                   // 32*128*4   = 16 KB
    unsigned short* w1h = (unsigned short*)(ws + 16384);                  // 128*64*2   = 16 KB
    unsigned short* w1l = (unsigned short*)(ws + 32768);                  // 16 KB
    float* scores       = (float*)(ws + 49152);                           // 32*16384*4 = 2 MB
    float* tau          = (float*)(ws + 49152 + 2097152);                 // 128 B
    float* u            = (float*)(ws + 49152 + 2097152 + 256);           // 16 KB

    k0_prep<<<33, 128, 0, stream>>>(x_query, wq1, bq1, wq2, bq2, wqp, bqp, wkp,
                                    wx1, wx2, r_buf, w1h, w1l);
    k1_items<<<(BATCH * NITEMS) / 64, 256, 0, stream>>>(x_items, w1h, w1l, bx1, r_buf, scores);
    k2_tau<<<BATCH, 1024, 0, stream>>>(scores, tau, u);
    k3_support<<<BATCH * 32, 256, 0, stream>>>(scores, tau, x_items, wx1, bx1, wx2, bx2, u);
    k4_head<<<BATCH, 128, 0, stream>>>(u, wvp, bvp, wp1, bp1, wp2, bp2, out);
}

// Round 4
// 334.310 us; speedup vs baseline: 1.7908x; 1.0119x over previous
//
#include <hip/hip_runtime.h>
#include <hip/hip_bf16.h>
#include <cstdint>

#define BATCH 32
#define NITEMS 16384
#define DEMB 128
#define IDIM 64

typedef short short8 __attribute__((ext_vector_type(8)));
typedef float f32x4 __attribute__((ext_vector_type(4)));

// ---------- helpers ----------
__device__ inline unsigned short f2bf(float f) {
    union { float f; unsigned int u; } v; v.f = f;
    unsigned int u = v.u;
    unsigned int r = (u + 0x7FFFu + ((u >> 16) & 1u)) >> 16;   // RNE, data is finite
    return (unsigned short)r;
}
__device__ inline float bf2f(unsigned short h) {
    union { unsigned int u; float f; } v; v.u = ((unsigned int)h) << 16;
    return v.f;
}

// gelu via A&S 7.1.28: erf(y) = 1 - (1+a1 y+...+a6 y^6)^-16, |err|<=3e-7, y>=0.
// Phi(x) = x>0 ? 1-0.5r : 0.5r with r = D^-16 at y=|x|/sqrt2. One rcp, no exp.
__device__ inline float gelu_f(float x) {
    float y = fabsf(x) * 0.70710678118654752f;
    float d = fmaf(y, 0.0000430638f, 0.0002765672f);
    d = fmaf(d, y, 0.0001520143f);
    d = fmaf(d, y, 0.0092705272f);
    d = fmaf(d, y, 0.0422820123f);
    d = fmaf(d, y, 0.0705230784f);
    d = fmaf(d, y, 1.0f);
    float s = d * d;   // d^2
    s = s * s;         // d^4
    s = s * s;         // d^8
    s = s * s;         // d^16
    float pe = 0.5f * __builtin_amdgcn_rcpf(s);
    float phi = (x > 0.f) ? (1.0f - pe) : pe;
    return x * phi;
}

// ---------- kernel 0: query path -> r[b] ; split-bf16 weight prep ----------
__global__ __launch_bounds__(128) void k0_prep(
    const float* __restrict__ xq, const float* __restrict__ wq1, const float* __restrict__ bq1,
    const float* __restrict__ wq2, const float* __restrict__ bq2,
    const float* __restrict__ wqp, const float* __restrict__ bqp,
    const float* __restrict__ wkp,
    const float* __restrict__ wx1, const float* __restrict__ wx2,
    float* __restrict__ r_out, unsigned short* __restrict__ w1h, unsigned short* __restrict__ w1l) {
    __shared__ float buf1[128], buf2[128], buf3[128], buf4[128];
    int t = threadIdx.x;
    int blk = blockIdx.x;
    if (blk < BATCH) {
        int b = blk;
        float xqv = xq[b];
        buf1[t] = gelu_f(fmaf(xqv, wq1[t], bq1[t]));
        __syncthreads();
        float acc = bq2[t];
        for (int j = 0; j < 128; j++) acc = fmaf(buf1[j], wq2[j * 128 + t], acc);
        buf2[t] = acc;
        __syncthreads();
        acc = bqp[t];
        for (int j = 0; j < 128; j++) acc = fmaf(buf2[j], wqp[j * 128 + t], acc);
        buf3[t] = acc;                       // q[b]
        __syncthreads();
        acc = 0.f;
        for (int i = 0; i < 128; i++) acc = fmaf(wkp[t * 128 + i], buf3[i], acc);
        buf4[t] = acc * 0.08838834764831845f; // qt = (wkp @ q) * 128^-0.5
        __syncthreads();
        acc = 0.f;
        for (int i = 0; i < 128; i++) acc = fmaf(wx2[t * 128 + i], buf4[i], acc);
        r_out[b * 128 + t] = acc;            // r = wx2 @ qt  (score[n] = h1g[n] . r[b] + const)
    } else {
        // wx1 [64][128] -> w1h/w1l [n=128][k=64] bf16 hi/lo split
        for (int idx = t; idx < 64 * 128; idx += 128) {
            int k = idx >> 7, n = idx & 127;
            float v = wx1[idx];
            unsigned short hi = f2bf(v);
            float lo = v - bf2f(hi);
            w1h[n * 64 + k] = hi;
            w1l[n * 64 + k] = f2bf(lo);
        }
    }
}

// stage one 64x64 fp32 tile (held in regs) as trunc hi/lo bf16 into LDS (pad 72)
__device__ inline void stage_tile(const float4* v, unsigned short* dh, unsigned short* dl,
                                  const int* srow, const int* sc4) {
    for (int p = 0; p < 4; p++) {
        float4 w = v[p];
        unsigned int ux = __float_as_uint(w.x), uy = __float_as_uint(w.y);
        unsigned int uz = __float_as_uint(w.z), uw = __float_as_uint(w.w);
        unsigned int hi01 = __builtin_amdgcn_perm(uy, ux, 0x07060302u);
        unsigned int hi23 = __builtin_amdgcn_perm(uw, uz, 0x07060302u);
        float lx = w.x - __uint_as_float(ux & 0xFFFF0000u);
        float ly = w.y - __uint_as_float(uy & 0xFFFF0000u);
        float lz = w.z - __uint_as_float(uz & 0xFFFF0000u);
        float lw = w.w - __uint_as_float(uw & 0xFFFF0000u);
        unsigned int lo01 = __builtin_amdgcn_perm(__float_as_uint(ly), __float_as_uint(lx), 0x07060302u);
        unsigned int lo23 = __builtin_amdgcn_perm(__float_as_uint(lw), __float_as_uint(lz), 0x07060302u);
        *(uint2*)(dh + srow[p] * 72 + sc4[p]) = make_uint2(hi01, hi23);
        *(uint2*)(dl + srow[p] * 72 + sc4[p]) = make_uint2(lo01, lo23);
    }
}

// ---------- kernel 1: per-item GEMM1 (split-bf16 MFMA) + gelu + score dot ----------
// 4 tiles of 64 items per block, software-pipelined: ping-pong LDS, register
// prefetch of tile t+1 under MFMA+gelu of tile t, ONE barrier per tile.
// 256 threads = 4 waves; each wave owns a 32-wide n-slice (nt split).
__global__ __launch_bounds__(256) void k1_items(
    const float* __restrict__ x, const unsigned short* __restrict__ w1h,
    const unsigned short* __restrict__ w1l, const float* __restrict__ bx1,
    const float* __restrict__ r_in, float* __restrict__ scores) {
    __shared__ alignas(16) unsigned short lxh[2][64 * 72];
    __shared__ alignas(16) unsigned short lxl[2][64 * 72];
    __shared__ float red[2][4][64];
    int tid = threadIdx.x;
    int wave = tid >> 6, lane = tid & 63;
    int quad = lane >> 4, l15 = lane & 15;
    int blk = blockIdx.x;
    int b = blk >> 6;                        // 64 blocks (256 items) per batch
    const float* xg = x + (size_t)blk * 256 * 64;

    // resident B fragments (K=64 -> 2 k-steps; 2 n-tiles of 16 per wave)
    short8 bh[2][2], bl[2][2];
    {
        int nb = wave * 32 + l15;
        for (int s = 0; s < 2; s++)
            for (int nt = 0; nt < 2; nt++) {
                int off = (nb + nt * 16) * 64 + s * 32 + quad * 8;
                bh[s][nt] = *(const short8*)(w1h + off);
                bl[s][nt] = *(const short8*)(w1l + off);
            }
    }
    float bias[2], rv[2];
    for (int nt = 0; nt < 2; nt++) {
        int c = wave * 32 + nt * 16 + l15;
        bias[nt] = bx1[c];
        rv[nt] = r_in[b * 128 + c];
    }

    int srow[4], sc4[4];
    for (int p = 0; p < 4; p++) {
        int idx = tid + p * 256;
        srow[p] = idx >> 4;
        sc4[p] = (idx & 15) * 4;
    }

    // prologue: load + stage tile 0 into buf 0
    float4 v[4];
    for (int p = 0; p < 4; p++)
        v[p] = *(const float4*)(xg + srow[p] * 64 + sc4[p]);
    stage_tile(v, lxh[0], lxl[0], srow, sc4);
    __syncthreads();

    for (int t = 0; t < 4; t++) {
        int pb = t & 1;
        // prefetch next tile into registers (latency hidden under MFMA+gelu)
        if (t < 3) {
            const float* xt = xg + (t + 1) * 4096;
            for (int p = 0; p < 4; p++)
                v[p] = *(const float4*)(xt + srow[p] * 64 + sc4[p]);
        }

        f32x4 acc[4][2];
        for (int mt = 0; mt < 4; mt++) for (int nt = 0; nt < 2; nt++) acc[mt][nt] = (f32x4)0.f;
        const unsigned short* bufh = lxh[pb];
        const unsigned short* bufl = lxl[pb];
        for (int s = 0; s < 2; s++) {
            int koff = s * 32 + quad * 8;
            short8 ah[4], al[4];
            for (int mt = 0; mt < 4; mt++) {
                int rb = (mt * 16 + l15) * 72 + koff;
                ah[mt] = *(const short8*)(bufh + rb);
                al[mt] = *(const short8*)(bufl + rb);
            }
            for (int mt = 0; mt < 4; mt++)
                for (int nt = 0; nt < 2; nt++) {
                    acc[mt][nt] = __builtin_amdgcn_mfma_f32_16x16x32_bf16(al[mt], bh[s][nt], acc[mt][nt], 0, 0, 0);
                    acc[mt][nt] = __builtin_amdgcn_mfma_f32_16x16x32_bf16(ah[mt], bl[s][nt], acc[mt][nt], 0, 0, 0);
                    acc[mt][nt] = __builtin_amdgcn_mfma_f32_16x16x32_bf16(ah[mt], bh[s][nt], acc[mt][nt], 0, 0, 0);
                }
        }

        // epilogue: bias + gelu + dot with r[b], reduce over the 16-lane quad group
        float pr[4][4];
        for (int mt = 0; mt < 4; mt++) for (int rr = 0; rr < 4; rr++) pr[mt][rr] = 0.f;
        for (int mt = 0; mt < 4; mt++)
            for (int nt = 0; nt < 2; nt++)
                for (int rr = 0; rr < 4; rr++) {
                    float g = gelu_f(acc[mt][nt][rr] + bias[nt]);
                    pr[mt][rr] = fmaf(g, rv[nt], pr[mt][rr]);
                }
        for (int off = 1; off < 16; off <<= 1)
            for (int mt = 0; mt < 4; mt++)
                for (int rr = 0; rr < 4; rr++)
                    pr[mt][rr] += __shfl_xor(pr[mt][rr], off);
        if (l15 == 0)
            for (int mt = 0; mt < 4; mt++)
                for (int rr = 0; rr < 4; rr++)
                    red[pb][wave][mt * 16 + quad * 4 + rr] = pr[mt][rr];

        // stage prefetched tile into the other buffer
        if (t < 3)
            stage_tile(v, lxh[1 - pb], lxl[1 - pb], srow, sc4);

        __syncthreads();

        if (tid < 64)
            scores[(size_t)blk * 256 + t * 64 + tid] =
                red[pb][0][tid] + red[pb][1][tid] + red[pb][2][tid] + red[pb][3][tid];
    }
}

// ---------- kernel 2: sparsemax tau per batch (Michelot fixed point) + zero u ----------
__global__ __launch_bounds__(1024) void k2_tau(const float* __restrict__ scores,
                                               float* __restrict__ tau_out,
                                               float* __restrict__ u) {
    __shared__ float la[2][16], lc[2][16];
    int b = blockIdx.x, t = threadIdx.x;
    int wid = t >> 6, lane = t & 63;
    const float* s = scores + (size_t)b * NITEMS;
    float z[16];
    for (int i = 0; i < 16; i++) z[i] = s[t + i * 1024];
    float sm = 0.f;
    for (int i = 0; i < 16; i++) sm += z[i];
    for (int off = 32; off; off >>= 1) sm += __shfl_xor(sm, off);
    if (lane == 0) la[1][wid] = sm;
    __syncthreads();
    float tot = 0.f;
    for (int i = 0; i < 16; i++) tot += la[1][i];
    float tau = (tot - 1.0f) * (1.0f / 16384.0f);
    for (int it = 0; it < 20; it++) {
        int pb = it & 1;
        float ls = 0.f, ct = 0.f;
        for (int i = 0; i < 16; i++) {
            bool a = z[i] > tau;
            ls += a ? z[i] : 0.f;
            ct += a ? 1.f : 0.f;
        }
        for (int off = 32; off; off >>= 1) {
            ls += __shfl_xor(ls, off);
            ct += __shfl_xor(ct, off);
        }
        if (lane == 0) { la[pb][wid] = ls; lc[pb][wid] = ct; }
        __syncthreads();
        float tls = 0.f, tct = 0.f;
        for (int i = 0; i < 16; i++) { tls += la[pb][i]; tct += lc[pb][i]; }
        tau = (tls - 1.0f) / tct;            // ct >= 1 always (max > tau)
    }
    if (t == 0) tau_out[b] = tau;
    if (t < 128) u[b * 128 + t] = 0.f;
}

// ---------- kernel 3: one wave per support item, fp32 recompute, shfl broadcasts ----------
__global__ __launch_bounds__(256) void k3_support(
    const float* __restrict__ scores, const float* __restrict__ tau_in,
    const float* __restrict__ x,
    const float* __restrict__ wx1, const float* __restrict__ bx1,
    const float* __restrict__ wx2, const float* __restrict__ bx2,
    float* __restrict__ u) {
    __shared__ float red[4][128];
    int blk = blockIdx.x;
    int b = blk >> 5;                 // 32 blocks per batch
    int sub = blk & 31;
    int wave = threadIdx.x >> 6, lane = threadIdx.x & 63;
    int wslot = sub * 4 + wave;       // 0..127 within batch
    int base = wslot * 128;           // this wave's 128-item slice
    float tau = tau_in[b];
    int t0 = lane, t1 = lane + 64;
    float bb0 = bx1[t0], bb1 = bx1[t1];
    float cc0 = bx2[t0], cc1 = bx2[t1];
    float u0 = 0.f, u1 = 0.f;
    const float* srow = scores + (size_t)b * NITEMS + base;
    for (int half = 0; half < 2; half++) {
        float sv = srow[half * 64 + lane] - tau;
        unsigned long long mask = __ballot(sv > 0.f);
        while (mask) {
            int src = __ffsll((long long)mask) - 1;
            mask &= mask - 1;
            float wgt = __shfl(sv, src);
            int item = base + half * 64 + src;
            const float* xr = x + ((size_t)b * NITEMS + item) * 64;
            float xv = xr[lane];
            float p0 = bb0, p1 = bb1;
            for (int k = 0; k < 64; k++) {
                float xk = __shfl(xv, k);
                p0 = fmaf(xk, wx1[k * 128 + t0], p0);
                p1 = fmaf(xk, wx1[k * 128 + t1], p1);
            }
            float h0 = gelu_f(p0), h1 = gelu_f(p1);
            float a0 = cc0, a1 = cc1;
            for (int j = 0; j < 64; j++) {
                float hj = __shfl(h0, j);
                a0 = fmaf(hj, wx2[j * 128 + t0], a0);
                a1 = fmaf(hj, wx2[j * 128 + t1], a1);
            }
            for (int j = 0; j < 64; j++) {
                float hj = __shfl(h1, j);
                a0 = fmaf(hj, wx2[(j + 64) * 128 + t0], a0);
                a1 = fmaf(hj, wx2[(j + 64) * 128 + t1], a1);
            }
            u0 = fmaf(wgt, a0, u0);
            u1 = fmaf(wgt, a1, u1);
        }
    }
    red[wave][t0] = u0;
    red[wave][t1] = u1;
    __syncthreads();
    if (threadIdx.x < 128) {
        float s = red[0][threadIdx.x] + red[1][threadIdx.x] +
                  red[2][threadIdx.x] + red[3][threadIdx.x];
        atomicAdd(&u[b * 128 + threadIdx.x], s);
    }
}

// ---------- kernel 4: z = u@wvp + bvp ; out = gelu(z@wp1+bp1)@wp2 + bp2 ----------
__global__ __launch_bounds__(128) void k4_head(
    const float* __restrict__ u, const float* __restrict__ wvp, const float* __restrict__ bvp,
    const float* __restrict__ wp1, const float* __restrict__ bp1,
    const float* __restrict__ wp2, const float* __restrict__ bp2,
    float* __restrict__ out) {
    __shared__ float ub[128], zb[128], tb[128];
    int b = blockIdx.x, t = threadIdx.x;
    ub[t] = u[b * 128 + t];
    __syncthreads();
    float z = bvp[t];
    for (int j = 0; j < 128; j++) z = fmaf(ub[j], wvp[j * 128 + t], z);
    zb[t] = z;
    __syncthreads();
    float h = bp1[t];
    for (int j = 0; j < 128; j++) h = fmaf(zb[j], wp1[j * 128 + t], h);
    tb[t] = gelu_f(h);
    __syncthreads();
    if (t < 10) {
        float o = bp2[t];
        for (int j = 0; j < 128; j++) o = fmaf(tb[j], wp2[j * 10 + t], o);
        out[b * 10 + t] = o;
    }
}

// ---------- launch ----------
extern "C" void kernel_launch(void* const* d_in, const int* in_sizes, int n_in,
                              void* d_out, int out_size, void* d_ws, size_t ws_size,
                              hipStream_t stream) {
    const float* x_items = (const float*)d_in[0];
    const float* x_query = (const float*)d_in[1];
    const float* wx1 = (const float*)d_in[2];
    const float* bx1 = (const float*)d_in[3];
    const float* wx2 = (const float*)d_in[4];
    const float* bx2 = (const float*)d_in[5];
    const float* wq1 = (const float*)d_in[6];
    const float* bq1 = (const float*)d_in[7];
    const float* wq2 = (const float*)d_in[8];
    const float* bq2 = (const float*)d_in[9];
    const float* wqp = (const float*)d_in[10];
    const float* bqp = (const float*)d_in[11];
    const float* wkp = (const float*)d_in[12];
    // d_in[13] = bkp: dropped (sparsemax shift invariance)
    const float* wvp = (const float*)d_in[14];
    const float* bvp = (const float*)d_in[15];
    const float* wp1 = (const float*)d_in[16];
    const float* bp1 = (const float*)d_in[17];
    const float* wp2 = (const float*)d_in[18];
    const float* bp2 = (const float*)d_in[19];
    float* out = (float*)d_out;

    char* ws = (char*)d_ws;
    float* r_buf        = (float*)(ws);                                   // 32*128*4   = 16 KB
    unsigned short* w1h = (unsigned short*)(ws + 16384);                  // 128*64*2   = 16 KB
    unsigned short* w1l = (unsigned short*)(ws + 32768);                  // 16 KB
    float* scores       = (float*)(ws + 49152);                           // 32*16384*4 = 2 MB
    float* tau          = (float*)(ws + 49152 + 2097152);                 // 128 B
    float* u            = (float*)(ws + 49152 + 2097152 + 256);           // 16 KB

    k0_prep<<<33, 128, 0, stream>>>(x_query, wq1, bq1, wq2, bq2, wqp, bqp, wkp,
                                    wx1, wx2, r_buf, w1h, w1l);
    k1_items<<<(BATCH * NITEMS) / 256, 256, 0, stream>>>(x_items, w1h, w1l, bx1, r_buf, scores);
    k2_tau<<<BATCH, 1024, 0, stream>>>(scores, tau, u);
    k3_support<<<BATCH * 32, 256, 0, stream>>>(scores, tau, x_items, wx1, bx1, wx2, bx2, u);
    k4_head<<<BATCH, 128, 0, stream>>>(u, wvp, bvp, wp1, bp1, wp2, bp2, out);
}

// Round 5
// 328.397 us; speedup vs baseline: 1.8231x; 1.0180x over previous
//
#include <hip/hip_runtime.h>
#include <hip/hip_bf16.h>
#include <cstdint>

#define BATCH 32
#define NITEMS 16384
#define DEMB 128
#define IDIM 64

typedef short short8 __attribute__((ext_vector_type(8)));
typedef float f32x4 __attribute__((ext_vector_type(4)));

// ---------- helpers ----------
__device__ inline unsigned short f2bf(float f) {
    union { float f; unsigned int u; } v; v.f = f;
    unsigned int u = v.u;
    unsigned int r = (u + 0x7FFFu + ((u >> 16) & 1u)) >> 16;   // RNE, data is finite
    return (unsigned short)r;
}
__device__ inline float bf2f(unsigned short h) {
    union { unsigned int u; float f; } v; v.u = ((unsigned int)h) << 16;
    return v.f;
}

// Exact-erf gelu via A&S 7.1.26 (|erf err| <= 1.5e-7), restructured:
// q = 0.5*(1-erf(|x|/sqrt2)) = P2(t)*exp2(-x^2*log2(e)/2), t = 1/(1+0.32759*|x|/sqrt2)
// gelu = x * (x>0 ? 1-q : q).  2 trans-pipe ops (rcp, exp2) co-issue with fma.
__device__ inline float gelu_f(float x) {
    float y = fabsf(x) * 0.70710678118654752f;
    float t = __builtin_amdgcn_rcpf(fmaf(0.3275911f, y, 1.0f));
    float p = fmaf(0.5307027145f, t, -0.7265760135f);     // a5/2, a4/2
    p = fmaf(p, t, 0.7107068705f);                        // a3/2
    p = fmaf(p, t, -0.142248368f);                        // a2/2
    p = fmaf(p, t, 0.127414796f);                         // a1/2
    p = p * t;
    float e = __builtin_amdgcn_exp2f(x * x * -0.72134752044448171f);
    float q = p * e;                                      // 0.5*erfc(y)
    float phi = (x > 0.f) ? (1.0f - q) : q;
    return x * phi;
}

// ---------- kernel 0: query path -> r[b] ; split-bf16 weight prep ----------
__global__ __launch_bounds__(128) void k0_prep(
    const float* __restrict__ xq, const float* __restrict__ wq1, const float* __restrict__ bq1,
    const float* __restrict__ wq2, const float* __restrict__ bq2,
    const float* __restrict__ wqp, const float* __restrict__ bqp,
    const float* __restrict__ wkp,
    const float* __restrict__ wx1, const float* __restrict__ wx2,
    float* __restrict__ r_out, unsigned short* __restrict__ w1h, unsigned short* __restrict__ w1l) {
    __shared__ float buf1[128], buf2[128], buf3[128], buf4[128];
    int t = threadIdx.x;
    int blk = blockIdx.x;
    if (blk < BATCH) {
        int b = blk;
        float xqv = xq[b];
        buf1[t] = gelu_f(fmaf(xqv, wq1[t], bq1[t]));
        __syncthreads();
        float acc = bq2[t];
        for (int j = 0; j < 128; j++) acc = fmaf(buf1[j], wq2[j * 128 + t], acc);
        buf2[t] = acc;
        __syncthreads();
        acc = bqp[t];
        for (int j = 0; j < 128; j++) acc = fmaf(buf2[j], wqp[j * 128 + t], acc);
        buf3[t] = acc;                       // q[b]
        __syncthreads();
        acc = 0.f;
        for (int i = 0; i < 128; i++) acc = fmaf(wkp[t * 128 + i], buf3[i], acc);
        buf4[t] = acc * 0.08838834764831845f; // qt = (wkp @ q) * 128^-0.5
        __syncthreads();
        acc = 0.f;
        for (int i = 0; i < 128; i++) acc = fmaf(wx2[t * 128 + i], buf4[i], acc);
        r_out[b * 128 + t] = acc;            // r = wx2 @ qt  (score[n] = h1g[n] . r[b] + const)
    } else {
        // wx1 [64][128] -> w1h/w1l [n=128][k=64] bf16 hi/lo split
        for (int idx = t; idx < 64 * 128; idx += 128) {
            int k = idx >> 7, n = idx & 127;
            float v = wx1[idx];
            unsigned short hi = f2bf(v);
            float lo = v - bf2f(hi);
            w1h[n * 64 + k] = hi;
            w1l[n * 64 + k] = f2bf(lo);
        }
    }
}

// ---------- kernel 1: per-item GEMM1 (split-bf16 MFMA) + gelu + score dot ----------
// R3 structure: 64 items per block, 8192 blocks, single LDS buffer (19 KB).
// 256 threads = 4 waves, each wave owns a 32-wide n-slice.
__global__ __launch_bounds__(256) void k1_items(
    const float* __restrict__ x, const unsigned short* __restrict__ w1h,
    const unsigned short* __restrict__ w1l, const float* __restrict__ bx1,
    const float* __restrict__ r_in, float* __restrict__ scores) {
    __shared__ alignas(16) unsigned short lxh[64 * 72];
    __shared__ alignas(16) unsigned short lxl[64 * 72];
    __shared__ float red[4][64];
    int tid = threadIdx.x;
    int wave = tid >> 6, lane = tid & 63;
    int quad = lane >> 4, l15 = lane & 15;
    int tile = blockIdx.x;
    long item0 = (long)tile * 64;
    int b = tile >> 8;                       // 256 tiles per batch

    // resident B fragments (K=64 -> 2 k-steps; 2 n-tiles of 16 per wave)
    short8 bh[2][2], bl[2][2];
    {
        int nb = wave * 32 + l15;
        for (int s = 0; s < 2; s++)
            for (int nt = 0; nt < 2; nt++) {
                int off = (nb + nt * 16) * 64 + s * 32 + quad * 8;
                bh[s][nt] = *(const short8*)(w1h + off);
                bl[s][nt] = *(const short8*)(w1l + off);
            }
    }
    float bias[2], rv[2];
    for (int nt = 0; nt < 2; nt++) {
        int c = wave * 32 + nt * 16 + l15;
        bias[nt] = bx1[c];
        rv[nt] = r_in[b * 128 + c];
    }

    // stage x tile [64 rows x 64 cols]: trunc hi/lo bf16 split via v_perm packing
    const float* xg = x + item0 * 64;
    for (int p = 0; p < 4; p++) {
        int idx = tid + p * 256;
        int row = idx >> 4, c4 = (idx & 15) * 4;
        float4 v = *(const float4*)(xg + row * 64 + c4);
        unsigned int ux = __float_as_uint(v.x), uy = __float_as_uint(v.y);
        unsigned int uz = __float_as_uint(v.z), uw = __float_as_uint(v.w);
        unsigned int hi01 = __builtin_amdgcn_perm(uy, ux, 0x07060302u);
        unsigned int hi23 = __builtin_amdgcn_perm(uw, uz, 0x07060302u);
        float lx = v.x - __uint_as_float(ux & 0xFFFF0000u);
        float ly = v.y - __uint_as_float(uy & 0xFFFF0000u);
        float lz = v.z - __uint_as_float(uz & 0xFFFF0000u);
        float lw = v.w - __uint_as_float(uw & 0xFFFF0000u);
        unsigned int lo01 = __builtin_amdgcn_perm(__float_as_uint(ly), __float_as_uint(lx), 0x07060302u);
        unsigned int lo23 = __builtin_amdgcn_perm(__float_as_uint(lw), __float_as_uint(lz), 0x07060302u);
        *(uint2*)(lxh + row * 72 + c4) = make_uint2(hi01, hi23);
        *(uint2*)(lxl + row * 72 + c4) = make_uint2(lo01, lo23);
    }
    __syncthreads();

    // acc init = bias (column-wise constant): folds the epilogue bias add into MFMA C
    f32x4 acc[4][2];
    for (int mt = 0; mt < 4; mt++)
        for (int nt = 0; nt < 2; nt++) {
            f32x4 bi = {bias[nt], bias[nt], bias[nt], bias[nt]};
            acc[mt][nt] = bi;
        }

    for (int s = 0; s < 2; s++) {
        int koff = s * 32 + quad * 8;
        short8 ah[4], al[4];
        for (int mt = 0; mt < 4; mt++) {
            int rb = (mt * 16 + l15) * 72 + koff;
            ah[mt] = *(const short8*)(lxh + rb);
            al[mt] = *(const short8*)(lxl + rb);
        }
        for (int mt = 0; mt < 4; mt++)
            for (int nt = 0; nt < 2; nt++) {
                acc[mt][nt] = __builtin_amdgcn_mfma_f32_16x16x32_bf16(al[mt], bh[s][nt], acc[mt][nt], 0, 0, 0);
                acc[mt][nt] = __builtin_amdgcn_mfma_f32_16x16x32_bf16(ah[mt], bl[s][nt], acc[mt][nt], 0, 0, 0);
                acc[mt][nt] = __builtin_amdgcn_mfma_f32_16x16x32_bf16(ah[mt], bh[s][nt], acc[mt][nt], 0, 0, 0);
            }
    }

    // epilogue: gelu + dot with r[b], reduce over the 16-lane quad group
    float pr[4][4];
    for (int mt = 0; mt < 4; mt++) for (int rr = 0; rr < 4; rr++) pr[mt][rr] = 0.f;
    for (int mt = 0; mt < 4; mt++)
        for (int nt = 0; nt < 2; nt++)
            for (int rr = 0; rr < 4; rr++) {
                float g = gelu_f(acc[mt][nt][rr]);
                pr[mt][rr] = fmaf(g, rv[nt], pr[mt][rr]);
            }
    for (int off = 1; off < 16; off <<= 1)
        for (int mt = 0; mt < 4; mt++)
            for (int rr = 0; rr < 4; rr++)
                pr[mt][rr] += __shfl_xor(pr[mt][rr], off);
    if (l15 == 0)
        for (int mt = 0; mt < 4; mt++)
            for (int rr = 0; rr < 4; rr++)
                red[wave][mt * 16 + quad * 4 + rr] = pr[mt][rr];
    __syncthreads();
    if (tid < 64)
        scores[item0 + tid] = red[0][tid] + red[1][tid] + red[2][tid] + red[3][tid];
}

// ---------- kernel 2: sparsemax tau per batch (Michelot fixed point) + zero u ----------
__global__ __launch_bounds__(1024) void k2_tau(const float* __restrict__ scores,
                                               float* __restrict__ tau_out,
                                               float* __restrict__ u) {
    __shared__ float la[2][16], lc[2][16];
    int b = blockIdx.x, t = threadIdx.x;
    int wid = t >> 6, lane = t & 63;
    const float* s = scores + (size_t)b * NITEMS;
    float z[16];
    for (int i = 0; i < 16; i++) z[i] = s[t + i * 1024];
    float sm = 0.f;
    for (int i = 0; i < 16; i++) sm += z[i];
    for (int off = 32; off; off >>= 1) sm += __shfl_xor(sm, off);
    if (lane == 0) la[1][wid] = sm;
    __syncthreads();
    float tot = 0.f;
    for (int i = 0; i < 16; i++) tot += la[1][i];
    float tau = (tot - 1.0f) * (1.0f / 16384.0f);
    for (int it = 0; it < 20; it++) {
        int pb = it & 1;
        float ls = 0.f, ct = 0.f;
        for (int i = 0; i < 16; i++) {
            bool a = z[i] > tau;
            ls += a ? z[i] : 0.f;
            ct += a ? 1.f : 0.f;
        }
        for (int off = 32; off; off >>= 1) {
            ls += __shfl_xor(ls, off);
            ct += __shfl_xor(ct, off);
        }
        if (lane == 0) { la[pb][wid] = ls; lc[pb][wid] = ct; }
        __syncthreads();
        float tls = 0.f, tct = 0.f;
        for (int i = 0; i < 16; i++) { tls += la[pb][i]; tct += lc[pb][i]; }
        tau = (tls - 1.0f) / tct;            // ct >= 1 always (max > tau)
    }
    if (t == 0) tau_out[b] = tau;
    if (t < 128) u[b * 128 + t] = 0.f;
}

// ---------- kernel 3: one wave per support item, fp32 recompute, shfl broadcasts ----------
__global__ __launch_bounds__(256) void k3_support(
    const float* __restrict__ scores, const float* __restrict__ tau_in,
    const float* __restrict__ x,
    const float* __restrict__ wx1, const float* __restrict__ bx1,
    const float* __restrict__ wx2, const float* __restrict__ bx2,
    float* __restrict__ u) {
    __shared__ float red[4][128];
    int blk = blockIdx.x;
    int b = blk >> 5;                 // 32 blocks per batch
    int sub = blk & 31;
    int wave = threadIdx.x >> 6, lane = threadIdx.x & 63;
    int wslot = sub * 4 + wave;       // 0..127 within batch
    int base = wslot * 128;           // this wave's 128-item slice
    float tau = tau_in[b];
    int t0 = lane, t1 = lane + 64;
    float bb0 = bx1[t0], bb1 = bx1[t1];
    float cc0 = bx2[t0], cc1 = bx2[t1];
    float u0 = 0.f, u1 = 0.f;
    const float* srow = scores + (size_t)b * NITEMS + base;
    for (int half = 0; half < 2; half++) {
        float sv = srow[half * 64 + lane] - tau;
        unsigned long long mask = __ballot(sv > 0.f);
        while (mask) {
            int src = __ffsll((long long)mask) - 1;
            mask &= mask - 1;
            float wgt = __shfl(sv, src);
            int item = base + half * 64 + src;
            const float* xr = x + ((size_t)b * NITEMS + item) * 64;
            float xv = xr[lane];
            float p0 = bb0, p1 = bb1;
            for (int k = 0; k < 64; k++) {
                float xk = __shfl(xv, k);
                p0 = fmaf(xk, wx1[k * 128 + t0], p0);
                p1 = fmaf(xk, wx1[k * 128 + t1], p1);
            }
            float h0 = gelu_f(p0), h1 = gelu_f(p1);
            float a0 = cc0, a1 = cc1;
            for (int j = 0; j < 64; j++) {
                float hj = __shfl(h0, j);
                a0 = fmaf(hj, wx2[j * 128 + t0], a0);
                a1 = fmaf(hj, wx2[j * 128 + t1], a1);
            }
            for (int j = 0; j < 64; j++) {
                float hj = __shfl(h1, j);
                a0 = fmaf(hj, wx2[(j + 64) * 128 + t0], a0);
                a1 = fmaf(hj, wx2[(j + 64) * 128 + t1], a1);
            }
            u0 = fmaf(wgt, a0, u0);
            u1 = fmaf(wgt, a1, u1);
        }
    }
    red[wave][t0] = u0;
    red[wave][t1] = u1;
    __syncthreads();
    if (threadIdx.x < 128) {
        float s = red[0][threadIdx.x] + red[1][threadIdx.x] +
                  red[2][threadIdx.x] + red[3][threadIdx.x];
        atomicAdd(&u[b * 128 + threadIdx.x], s);
    }
}

// ---------- kernel 4: z = u@wvp + bvp ; out = gelu(z@wp1+bp1)@wp2 + bp2 ----------
__global__ __launch_bounds__(128) void k4_head(
    const float* __restrict__ u, const float* __restrict__ wvp, const float* __restrict__ bvp,
    const float* __restrict__ wp1, const float* __restrict__ bp1,
    const float* __restrict__ wp2, const float* __restrict__ bp2,
    float* __restrict__ out) {
    __shared__ float ub[128], zb[128], tb[128];
    int b = blockIdx.x, t = threadIdx.x;
    ub[t] = u[b * 128 + t];
    __syncthreads();
    float z = bvp[t];
    for (int j = 0; j < 128; j++) z = fmaf(ub[j], wvp[j * 128 + t], z);
    zb[t] = z;
    __syncthreads();
    float h = bp1[t];
    for (int j = 0; j < 128; j++) h = fmaf(zb[j], wp1[j * 128 + t], h);
    tb[t] = gelu_f(h);
    __syncthreads();
    if (t < 10) {
        float o = bp2[t];
        for (int j = 0; j < 128; j++) o = fmaf(tb[j], wp2[j * 10 + t], o);
        out[b * 10 + t] = o;
    }
}

// ---------- launch ----------
extern "C" void kernel_launch(void* const* d_in, const int* in_sizes, int n_in,
                              void* d_out, int out_size, void* d_ws, size_t ws_size,
                              hipStream_t stream) {
    const float* x_items = (const float*)d_in[0];
    const float* x_query = (const float*)d_in[1];
    const float* wx1 = (const float*)d_in[2];
    const float* bx1 = (const float*)d_in[3];
    const float* wx2 = (const float*)d_in[4];
    const float* bx2 = (const float*)d_in[5];
    const float* wq1 = (const float*)d_in[6];
    const float* bq1 = (const float*)d_in[7];
    const float* wq2 = (const float*)d_in[8];
    const float* bq2 = (const float*)d_in[9];
    const float* wqp = (const float*)d_in[10];
    const float* bqp = (const float*)d_in[11];
    const float* wkp = (const float*)d_in[12];
    // d_in[13] = bkp: dropped (sparsemax shift invariance)
    const float* wvp = (const float*)d_in[14];
    const float* bvp = (const float*)d_in[15];
    const float* wp1 = (const float*)d_in[16];
    const float* bp1 = (const float*)d_in[17];
    const float* wp2 = (const float*)d_in[18];
    const float* bp2 = (const float*)d_in[19];
    float* out = (float*)d_out;

    char* ws = (char*)d_ws;
    float* r_buf        = (float*)(ws);                                   // 32*128*4   = 16 KB
    unsigned short* w1h = (unsigned short*)(ws + 16384);                  // 128*64*2   = 16 KB
    unsigned short* w1l = (unsigned short*)(ws + 32768);                  // 16 KB
    float* scores       = (float*)(ws + 49152);                           // 32*16384*4 = 2 MB
    float* tau          = (float*)(ws + 49152 + 2097152);                 // 128 B
    float* u            = (float*)(ws + 49152 + 2097152 + 256);           // 16 KB

    k0_prep<<<33, 128, 0, stream>>>(x_query, wq1, bq1, wq2, bq2, wqp, bqp, wkp,
                                    wx1, wx2, r_buf, w1h, w1l);
    k1_items<<<(BATCH * NITEMS) / 64, 256, 0, stream>>>(x_items, w1h, w1l, bx1, r_buf, scores);
    k2_tau<<<BATCH, 1024, 0, stream>>>(scores, tau, u);
    k3_support<<<BATCH * 32, 256, 0, stream>>>(scores, tau, x_items, wx1, bx1, wx2, bx2, u);
    k4_head<<<BATCH, 128, 0, stream>>>(u, wvp, bvp, wp1, bp1, wp2, bp2, out);
}

// Round 6
// 325.922 us; speedup vs baseline: 1.8369x; 1.0076x over previous
//
#include <hip/hip_runtime.h>
#include <hip/hip_bf16.h>
#include <cstdint>

#define BATCH 32
#define NITEMS 16384
#define DEMB 128
#define IDIM 64

typedef short short8 __attribute__((ext_vector_type(8)));
typedef float f32x4 __attribute__((ext_vector_type(4)));

// ---------- helpers ----------
__device__ inline unsigned short f2bf(float f) {
    union { float f; unsigned int u; } v; v.f = f;
    unsigned int u = v.u;
    unsigned int r = (u + 0x7FFFu + ((u >> 16) & 1u)) >> 16;   // RNE, data is finite
    return (unsigned short)r;
}
__device__ inline float bf2f(unsigned short h) {
    union { unsigned int u; float f; } v; v.u = ((unsigned int)h) << 16;
    return v.f;
}

// Exact-erf gelu via A&S 7.1.26 (|erf err| <= 1.5e-7), restructured:
// q = 0.5*(1-erf(|x|/sqrt2)) = P2(t)*exp2(-x^2*log2(e)/2), t = 1/(1+0.32759*|x|/sqrt2)
// gelu = x * (x>0 ? 1-q : q).  2 trans-pipe ops (rcp, exp2) co-issue with fma.
__device__ inline float gelu_f(float x) {
    float y = fabsf(x) * 0.70710678118654752f;
    float t = __builtin_amdgcn_rcpf(fmaf(0.3275911f, y, 1.0f));
    float p = fmaf(0.5307027145f, t, -0.7265760135f);     // a5/2, a4/2
    p = fmaf(p, t, 0.7107068705f);                        // a3/2
    p = fmaf(p, t, -0.142248368f);                        // a2/2
    p = fmaf(p, t, 0.127414796f);                         // a1/2
    p = p * t;
    float e = __builtin_amdgcn_exp2f(x * x * -0.72134752044448171f);
    float q = p * e;                                      // 0.5*erfc(y)
    float phi = (x > 0.f) ? (1.0f - q) : q;
    return x * phi;
}

// ---------- kernel 0: query path -> r[b] ; split-bf16 weight prep ----------
__global__ __launch_bounds__(128) void k0_prep(
    const float* __restrict__ xq, const float* __restrict__ wq1, const float* __restrict__ bq1,
    const float* __restrict__ wq2, const float* __restrict__ bq2,
    const float* __restrict__ wqp, const float* __restrict__ bqp,
    const float* __restrict__ wkp,
    const float* __restrict__ wx1, const float* __restrict__ wx2,
    float* __restrict__ r_out, unsigned short* __restrict__ w1h, unsigned short* __restrict__ w1l) {
    __shared__ float buf1[128], buf2[128], buf3[128], buf4[128];
    int t = threadIdx.x;
    int blk = blockIdx.x;
    if (blk < BATCH) {
        int b = blk;
        float xqv = xq[b];
        buf1[t] = gelu_f(fmaf(xqv, wq1[t], bq1[t]));
        __syncthreads();
        float acc = bq2[t];
        for (int j = 0; j < 128; j++) acc = fmaf(buf1[j], wq2[j * 128 + t], acc);
        buf2[t] = acc;
        __syncthreads();
        acc = bqp[t];
        for (int j = 0; j < 128; j++) acc = fmaf(buf2[j], wqp[j * 128 + t], acc);
        buf3[t] = acc;                       // q[b]
        __syncthreads();
        acc = 0.f;
        for (int i = 0; i < 128; i++) acc = fmaf(wkp[t * 128 + i], buf3[i], acc);
        buf4[t] = acc * 0.08838834764831845f; // qt = (wkp @ q) * 128^-0.5
        __syncthreads();
        acc = 0.f;
        for (int i = 0; i < 128; i++) acc = fmaf(wx2[t * 128 + i], buf4[i], acc);
        r_out[b * 128 + t] = acc;            // r = wx2 @ qt  (score[n] = h1g[n] . r[b] + const)
    } else {
        // wx1 [64][128] -> w1h/w1l [n=128][k=64] bf16 hi/lo split
        for (int idx = t; idx < 64 * 128; idx += 128) {
            int k = idx >> 7, n = idx & 127;
            float v = wx1[idx];
            unsigned short hi = f2bf(v);
            float lo = v - bf2f(hi);
            w1h[n * 64 + k] = hi;
            w1l[n * 64 + k] = f2bf(lo);
        }
    }
}

// ---------- kernel 1: per-item GEMM1 (split-bf16 MFMA) + gelu + score dot ----------
// TRANSPOSED: C = W1 (A, M=128 n-dims) x X^T (B, N=64 items), K=64.
// C rows = h1-dims, C cols = items -> score dot over n-dims is per-lane FMA +
// 2-step quad shuffle (8 DS ops) instead of a 4-step 16-lane butterfly (64).
// 64 items per block, 256 threads = 4 waves; wave owns 32 rows (2 m-tiles).
__global__ __launch_bounds__(256) void k1_items(
    const float* __restrict__ x, const unsigned short* __restrict__ w1h,
    const unsigned short* __restrict__ w1l, const float* __restrict__ bx1,
    const float* __restrict__ r_in, float* __restrict__ scores) {
    __shared__ alignas(16) unsigned short lxh[64 * 72];
    __shared__ alignas(16) unsigned short lxl[64 * 72];
    __shared__ float red[4][64];
    int tid = threadIdx.x;
    int wave = tid >> 6, lane = tid & 63;
    int quad = lane >> 4, l15 = lane & 15;
    int tile = blockIdx.x;
    long item0 = (long)tile * 64;
    int b = tile >> 8;                       // 256 tiles per batch

    // resident A fragments = weights: rows wave*32 + mt*16 + l15, k-contig
    short8 wh[2][2], wl[2][2];               // [s][mt]
    for (int s = 0; s < 2; s++)
        for (int mt = 0; mt < 2; mt++) {
            int off = (wave * 32 + mt * 16 + l15) * 64 + s * 32 + quad * 8;
            wh[s][mt] = *(const short8*)(w1h + off);
            wl[s][mt] = *(const short8*)(w1l + off);
        }
    // per-lane row constants: row = wave*32 + mt*16 + quad*4 + rr
    float bias8[2][4], rv8[2][4];
    for (int mt = 0; mt < 2; mt++)
        for (int rr = 0; rr < 4; rr++) {
            int row = wave * 32 + mt * 16 + quad * 4 + rr;
            bias8[mt][rr] = bx1[row];
            rv8[mt][rr] = r_in[b * 128 + row];
        }

    // stage x tile [64 items x 64 k]: trunc hi/lo bf16 split via v_perm packing
    const float* xg = x + item0 * 64;
    for (int p = 0; p < 4; p++) {
        int idx = tid + p * 256;
        int row = idx >> 4, c4 = (idx & 15) * 4;
        float4 v = *(const float4*)(xg + row * 64 + c4);
        unsigned int ux = __float_as_uint(v.x), uy = __float_as_uint(v.y);
        unsigned int uz = __float_as_uint(v.z), uw = __float_as_uint(v.w);
        unsigned int hi01 = __builtin_amdgcn_perm(uy, ux, 0x07060302u);
        unsigned int hi23 = __builtin_amdgcn_perm(uw, uz, 0x07060302u);
        float lx = v.x - __uint_as_float(ux & 0xFFFF0000u);
        float ly = v.y - __uint_as_float(uy & 0xFFFF0000u);
        float lz = v.z - __uint_as_float(uz & 0xFFFF0000u);
        float lw = v.w - __uint_as_float(uw & 0xFFFF0000u);
        unsigned int lo01 = __builtin_amdgcn_perm(__float_as_uint(ly), __float_as_uint(lx), 0x07060302u);
        unsigned int lo23 = __builtin_amdgcn_perm(__float_as_uint(lw), __float_as_uint(lz), 0x07060302u);
        *(uint2*)(lxh + row * 72 + c4) = make_uint2(hi01, hi23);
        *(uint2*)(lxl + row * 72 + c4) = make_uint2(lo01, lo23);
    }
    __syncthreads();

    // acc init = bias (row-wise constant, folded into MFMA C)
    f32x4 acc[2][4];                         // [mt][nt]
    for (int mt = 0; mt < 2; mt++)
        for (int nt = 0; nt < 4; nt++) {
            f32x4 bi = {bias8[mt][0], bias8[mt][1], bias8[mt][2], bias8[mt][3]};
            acc[mt][nt] = bi;
        }

    for (int s = 0; s < 2; s++) {
        int koff = s * 32 + quad * 8;
        short8 xh[4], xl[4];                 // B fragments: col = nt*16 + l15
        for (int nt = 0; nt < 4; nt++) {
            int rb = (nt * 16 + l15) * 72 + koff;
            xh[nt] = *(const short8*)(lxh + rb);
            xl[nt] = *(const short8*)(lxl + rb);
        }
        for (int mt = 0; mt < 2; mt++)
            for (int nt = 0; nt < 4; nt++) {
                acc[mt][nt] = __builtin_amdgcn_mfma_f32_16x16x32_bf16(wh[s][mt], xl[nt], acc[mt][nt], 0, 0, 0);
                acc[mt][nt] = __builtin_amdgcn_mfma_f32_16x16x32_bf16(wl[s][mt], xh[nt], acc[mt][nt], 0, 0, 0);
                acc[mt][nt] = __builtin_amdgcn_mfma_f32_16x16x32_bf16(wh[s][mt], xh[nt], acc[mt][nt], 0, 0, 0);
            }
    }

    // epilogue: gelu + dot with r over rows (per-lane), reduce over quad axis
    float pr[4] = {0.f, 0.f, 0.f, 0.f};      // per nt -> item nt*16 + l15
    for (int mt = 0; mt < 2; mt++)
        for (int nt = 0; nt < 4; nt++)
            for (int rr = 0; rr < 4; rr++) {
                float g = gelu_f(acc[mt][nt][rr]);
                pr[nt] = fmaf(g, rv8[mt][rr], pr[nt]);
            }
    for (int nt = 0; nt < 4; nt++) {
        pr[nt] += __shfl_xor(pr[nt], 16);
        pr[nt] += __shfl_xor(pr[nt], 32);
    }
    if (quad == 0)
        for (int nt = 0; nt < 4; nt++)
            red[wave][nt * 16 + l15] = pr[nt];
    __syncthreads();
    if (tid < 64)
        scores[item0 + tid] = red[0][tid] + red[1][tid] + red[2][tid] + red[3][tid];
}

// ---------- kernel 2: sparsemax tau per batch (Michelot fixed point) + zero u ----------
__global__ __launch_bounds__(1024) void k2_tau(const float* __restrict__ scores,
                                               float* __restrict__ tau_out,
                                               float* __restrict__ u) {
    __shared__ float la[2][16], lc[2][16];
    int b = blockIdx.x, t = threadIdx.x;
    int wid = t >> 6, lane = t & 63;
    const float* s = scores + (size_t)b * NITEMS;
    float z[16];
    for (int i = 0; i < 16; i++) z[i] = s[t + i * 1024];
    float sm = 0.f;
    for (int i = 0; i < 16; i++) sm += z[i];
    for (int off = 32; off; off >>= 1) sm += __shfl_xor(sm, off);
    if (lane == 0) la[1][wid] = sm;
    __syncthreads();
    float tot = 0.f;
    for (int i = 0; i < 16; i++) tot += la[1][i];
    float tau = (tot - 1.0f) * (1.0f / 16384.0f);
    for (int it = 0; it < 20; it++) {
        int pb = it & 1;
        float ls = 0.f, ct = 0.f;
        for (int i = 0; i < 16; i++) {
            bool a = z[i] > tau;
            ls += a ? z[i] : 0.f;
            ct += a ? 1.f : 0.f;
        }
        for (int off = 32; off; off >>= 1) {
            ls += __shfl_xor(ls, off);
            ct += __shfl_xor(ct, off);
        }
        if (lane == 0) { la[pb][wid] = ls; lc[pb][wid] = ct; }
        __syncthreads();
        float tls = 0.f, tct = 0.f;
        for (int i = 0; i < 16; i++) { tls += la[pb][i]; tct += lc[pb][i]; }
        tau = (tls - 1.0f) / tct;            // ct >= 1 always (max > tau)
    }
    if (t == 0) tau_out[b] = tau;
    if (t < 128) u[b * 128 + t] = 0.f;
}

// ---------- kernel 3: one wave per support item, fp32 recompute, shfl broadcasts ----------
__global__ __launch_bounds__(256) void k3_support(
    const float* __restrict__ scores, const float* __restrict__ tau_in,
    const float* __restrict__ x,
    const float* __restrict__ wx1, const float* __restrict__ bx1,
    const float* __restrict__ wx2, const float* __restrict__ bx2,
    float* __restrict__ u) {
    __shared__ float red[4][128];
    int blk = blockIdx.x;
    int b = blk >> 5;                 // 32 blocks per batch
    int sub = blk & 31;
    int wave = threadIdx.x >> 6, lane = threadIdx.x & 63;
    int wslot = sub * 4 + wave;       // 0..127 within batch
    int base = wslot * 128;           // this wave's 128-item slice
    float tau = tau_in[b];
    int t0 = lane, t1 = lane + 64;
    float bb0 = bx1[t0], bb1 = bx1[t1];
    float cc0 = bx2[t0], cc1 = bx2[t1];
    float u0 = 0.f, u1 = 0.f;
    const float* srow = scores + (size_t)b * NITEMS + base;
    for (int half = 0; half < 2; half++) {
        float sv = srow[half * 64 + lane] - tau;
        unsigned long long mask = __ballot(sv > 0.f);
        while (mask) {
            int src = __ffsll((long long)mask) - 1;
            mask &= mask - 1;
            float wgt = __shfl(sv, src);
            int item = base + half * 64 + src;
            const float* xr = x + ((size_t)b * NITEMS + item) * 64;
            float xv = xr[lane];
            float p0 = bb0, p1 = bb1;
            for (int k = 0; k < 64; k++) {
                float xk = __shfl(xv, k);
                p0 = fmaf(xk, wx1[k * 128 + t0], p0);
                p1 = fmaf(xk, wx1[k * 128 + t1], p1);
            }
            float h0 = gelu_f(p0), h1 = gelu_f(p1);
            float a0 = cc0, a1 = cc1;
            for (int j = 0; j < 64; j++) {
                float hj = __shfl(h0, j);
                a0 = fmaf(hj, wx2[j * 128 + t0], a0);
                a1 = fmaf(hj, wx2[j * 128 + t1], a1);
            }
            for (int j = 0; j < 64; j++) {
                float hj = __shfl(h1, j);
                a0 = fmaf(hj, wx2[(j + 64) * 128 + t0], a0);
                a1 = fmaf(hj, wx2[(j + 64) * 128 + t1], a1);
            }
            u0 = fmaf(wgt, a0, u0);
            u1 = fmaf(wgt, a1, u1);
        }
    }
    red[wave][t0] = u0;
    red[wave][t1] = u1;
    __syncthreads();
    if (threadIdx.x < 128) {
        float s = red[0][threadIdx.x] + red[1][threadIdx.x] +
                  red[2][threadIdx.x] + red[3][threadIdx.x];
        atomicAdd(&u[b * 128 + threadIdx.x], s);
    }
}

// ---------- kernel 4: z = u@wvp + bvp ; out = gelu(z@wp1+bp1)@wp2 + bp2 ----------
__global__ __launch_bounds__(128) void k4_head(
    const float* __restrict__ u, const float* __restrict__ wvp, const float* __restrict__ bvp,
    const float* __restrict__ wp1, const float* __restrict__ bp1,
    const float* __restrict__ wp2, const float* __restrict__ bp2,
    float* __restrict__ out) {
    __shared__ float ub[128], zb[128], tb[128];
    int b = blockIdx.x, t = threadIdx.x;
    ub[t] = u[b * 128 + t];
    __syncthreads();
    float z = bvp[t];
    for (int j = 0; j < 128; j++) z = fmaf(ub[j], wvp[j * 128 + t], z);
    zb[t] = z;
    __syncthreads();
    float h = bp1[t];
    for (int j = 0; j < 128; j++) h = fmaf(zb[j], wp1[j * 128 + t], h);
    tb[t] = gelu_f(h);
    __syncthreads();
    if (t < 10) {
        float o = bp2[t];
        for (int j = 0; j < 128; j++) o = fmaf(tb[j], wp2[j * 10 + t], o);
        out[b * 10 + t] = o;
    }
}

// ---------- launch ----------
extern "C" void kernel_launch(void* const* d_in, const int* in_sizes, int n_in,
                              void* d_out, int out_size, void* d_ws, size_t ws_size,
                              hipStream_t stream) {
    const float* x_items = (const float*)d_in[0];
    const float* x_query = (const float*)d_in[1];
    const float* wx1 = (const float*)d_in[2];
    const float* bx1 = (const float*)d_in[3];
    const float* wx2 = (const float*)d_in[4];
    const float* bx2 = (const float*)d_in[5];
    const float* wq1 = (const float*)d_in[6];
    const float* bq1 = (const float*)d_in[7];
    const float* wq2 = (const float*)d_in[8];
    const float* bq2 = (const float*)d_in[9];
    const float* wqp = (const float*)d_in[10];
    const float* bqp = (const float*)d_in[11];
    const float* wkp = (const float*)d_in[12];
    // d_in[13] = bkp: dropped (sparsemax shift invariance)
    const float* wvp = (const float*)d_in[14];
    const float* bvp = (const float*)d_in[15];
    const float* wp1 = (const float*)d_in[16];
    const float* bp1 = (const float*)d_in[17];
    const float* wp2 = (const float*)d_in[18];
    const float* bp2 = (const float*)d_in[19];
    float* out = (float*)d_out;

    char* ws = (char*)d_ws;
    float* r_buf        = (float*)(ws);                                   // 32*128*4   = 16 KB
    unsigned short* w1h = (unsigned short*)(ws + 16384);                  // 128*64*2   = 16 KB
    unsigned short* w1l = (unsigned short*)(ws + 32768);                  // 16 KB
    float* scores       = (float*)(ws + 49152);                           // 32*16384*4 = 2 MB
    float* tau          = (float*)(ws + 49152 + 2097152);                 // 128 B
    float* u            = (float*)(ws + 49152 + 2097152 + 256);           // 16 KB

    k0_prep<<<33, 128, 0, stream>>>(x_query, wq1, bq1, wq2, bq2, wqp, bqp, wkp,
                                    wx1, wx2, r_buf, w1h, w1l);
    k1_items<<<(BATCH * NITEMS) / 64, 256, 0, stream>>>(x_items, w1h, w1l, bx1, r_buf, scores);
    k2_tau<<<BATCH, 1024, 0, stream>>>(scores, tau, u);
    k3_support<<<BATCH * 32, 256, 0, stream>>>(scores, tau, x_items, wx1, bx1, wx2, bx2, u);
    k4_head<<<BATCH, 128, 0, stream>>>(u, wvp, bvp, wp1, bp1, wp2, bp2, out);
}